// Round 16
// baseline (364.967 us; speedup 1.0000x reference)
//
#include <hip/hip_runtime.h>
#include <hip/hip_bf16.h>
#include <cstddef>

#define C_DIM 256
#define HEADS 8
#define HD 32
#define NPTS 512
#define NFULL_N 65536
#define NRED_N 50000
#define NE_N 128

typedef __attribute__((ext_vector_type(8))) short short8;
typedef __attribute__((ext_vector_type(4))) float floatx4;
typedef __attribute__((ext_vector_type(4))) unsigned uintx4;

// ---------------------------------------------------------------- utilities
__device__ __forceinline__ float wave_reduce_sum(float v) {
#pragma unroll
  for (int off = 1; off < 64; off <<= 1) v += __shfl_xor(v, off, 64);
  return v;
}

__device__ __forceinline__ unsigned short f2bf(float f) {
  union { float f; unsigned u; } x; x.f = f;
  unsigned r = x.u + 0x7FFF + ((x.u >> 16) & 1);   // round-to-nearest-even
  return (unsigned short)(r >> 16);
}

__device__ __forceinline__ float bf2f(unsigned short u) {
  union { unsigned u; float f; } x; x.u = ((unsigned)u) << 16;
  return x.f;
}

__device__ __forceinline__ float fast_exp2(float x) {
#if __has_builtin(__builtin_amdgcn_exp2f)
  return __builtin_amdgcn_exp2f(x);
#else
  return exp2f(x);
#endif
}

__device__ __forceinline__ float fast_rcp(float x) {
#if __has_builtin(__builtin_amdgcn_rcpf)
  return __builtin_amdgcn_rcpf(x);
#else
  return 1.0f / x;
#endif
}

// XCD-aware bijective block remap: dispatch id -> logical id such that each
// XCD (hw: id % 8) owns a CONTIGUOUS logical range (per-XCD L2 reuse).
__device__ __forceinline__ int xcd_logical(int bid, int nwg) {
  int q = nwg >> 3, r = nwg & 7;
  int xcd = bid & 7, s = bid >> 3;
  int base = (xcd < r) ? xcd * (q + 1) : r * (q + 1) + (xcd - r) * q;
  return base + s;
}

// --------------------------------------------- all weights fp32 -> bf16, 1 launch
__global__ __launch_bounds__(256) void cvt_all_kernel(
    const float* __restrict__ qw, const float* __restrict__ kw,
    const float* __restrict__ vw, const float* __restrict__ ow,
    const float* __restrict__ w1, const float* __restrict__ w2,
    unsigned short* __restrict__ qwb, unsigned short* __restrict__ kwb,
    unsigned short* __restrict__ vwb, unsigned short* __restrict__ owb,
    unsigned short* __restrict__ w1b, unsigned short* __restrict__ w2b)
{
  int i = blockIdx.x * 256 + threadIdx.x;          // float4 index, total 114688
  const float* src; unsigned short* dst; int o;
  if      (i <  16384) { src = qw; dst = qwb; o = i; }
  else if (i <  32768) { src = kw; dst = kwb; o = i - 16384; }
  else if (i <  49152) { src = vw; dst = vwb; o = i - 32768; }
  else if (i <  65536) { src = ow; dst = owb; o = i - 49152; }
  else if (i <  98304) { src = w1; dst = w1b; o = i - 65536; }
  else                 { src = w2; dst = w2b; o = i - 98304; }
  float4 v = *(const float4*)&src[o << 2];
  unsigned u0 = f2bf(v.x) | ((unsigned)f2bf(v.y) << 16);
  unsigned u1 = f2bf(v.z) | ((unsigned)f2bf(v.w) << 16);
  *(uint2*)&dst[o << 2] = make_uint2(u0, u1);
}

// ------------------------- LayerNorm1 (gather, bf16 out) + fused segment cnt
__global__ __launch_bounds__(256) void ln_kernel(
    const float* __restrict__ x, const int* __restrict__ gidx,
    const float* __restrict__ w, const float* __restrict__ b,
    unsigned short* __restrict__ out, int nrows,
    const int* __restrict__ index, float* __restrict__ cnts)
{
  int wave = threadIdx.x >> 6, lane = threadIdx.x & 63;
  int row = blockIdx.x * 4 + wave;
  if (row >= nrows) return;
  int src = gidx ? gidx[row] : row;
  if (cnts && lane == 0) atomicAdd(&cnts[index[src]], 1.0f);
  const float* xr = x + (size_t)src * C_DIM;
  float4 v = *(const float4*)&xr[lane << 2];
  float s  = v.x + v.y + v.z + v.w;
  float sq = v.x*v.x + v.y*v.y + v.z*v.z + v.w*v.w;
  s  = wave_reduce_sum(s);
  sq = wave_reduce_sum(sq);
  float mean = s * (1.0f / 256.0f);
  float var  = sq * (1.0f / 256.0f) - mean * mean;
  float rstd = rsqrtf(var + 1e-5f);
  float4 wv = *(const float4*)&w[lane << 2];
  float4 bv = *(const float4*)&b[lane << 2];
  float ox = (v.x - mean) * rstd * wv.x + bv.x;
  float oy = (v.y - mean) * rstd * wv.y + bv.y;
  float oz = (v.z - mean) * rstd * wv.z + bv.z;
  float ow = (v.w - mean) * rstd * wv.w + bv.w;
  unsigned u0 = f2bf(ox) | ((unsigned)f2bf(oy) << 16);
  unsigned u1 = f2bf(oz) | ((unsigned)f2bf(ow) << 16);
  *(uint2*)&out[(size_t)row * C_DIM + (lane << 2)] = make_uint2(u0, u1);
}

// ---------------------------------------- fused QKV projection (bf16 per-head)
// 1D grid 2048, XCD-swizzled; 2-phase double-buffered staging.
__global__ __launch_bounds__(256) void qkv_kernel(
    const unsigned short* __restrict__ A,
    const unsigned short* __restrict__ Bq, const unsigned short* __restrict__ Bk,
    const unsigned short* __restrict__ Bv,
    unsigned short* __restrict__ qo, unsigned short* __restrict__ ko,
    unsigned short* __restrict__ vo)
{
  __shared__ unsigned short As[2][128 * 32];
  __shared__ unsigned short Bqs[2][64 * 32];
  __shared__ unsigned short Bks[2][64 * 32];
  __shared__ unsigned short Bvs[2][64 * 32];
  const int tid = threadIdx.x;
  const int lane = tid & 63, w = tid >> 6;
  const int wr = w >> 1, wc = w & 1;
  const int l15 = lane & 15, g = lane >> 4;
  const int L = xcd_logical(blockIdx.x, 2048);
  const int bn = L & 3;                     // 64-col slice (fastest)
  const int bm = (L >> 2) * 128;
  floatx4 acc[3][4][2] = {};
  const int sr = lane >> 2;
  const int sk = (lane & 3) << 3;

  auto stage = [&](int buf, int k0) {
#pragma unroll
    for (int c = 0; c < 2; ++c) {               // 8 A stripes, 2/wave
      int stripe = w * 2 + c;
      const unsigned short* ga = A + (size_t)(bm + stripe * 16 + sr) * 256 + k0 + sk;
      __builtin_amdgcn_global_load_lds(
          (const __attribute__((address_space(1))) void*)ga,
          (__attribute__((address_space(3))) void*)&As[buf][stripe * 512], 16, 0, 0);
    }
#pragma unroll
    for (int c = 0; c < 3; ++c) {               // 12 B stripes, 3/wave
      int idx = w * 3 + c;                      // 0..11
      int t = idx >> 2, rs = idx & 3;
      const unsigned short* Bt = (t == 0) ? Bq : (t == 1) ? Bk : Bv;
      unsigned short* ldst = (t == 0) ? &Bqs[buf][rs * 512]
                           : (t == 1) ? &Bks[buf][rs * 512] : &Bvs[buf][rs * 512];
      const unsigned short* gsrc = Bt + (size_t)(bn * 64 + rs * 16 + sr) * 256 + k0 + sk;
      __builtin_amdgcn_global_load_lds(
          (const __attribute__((address_space(1))) void*)gsrc,
          (__attribute__((address_space(3))) void*)ldst, 16, 0, 0);
    }
  };

  stage(0, 0);
  __syncthreads();                              // drain vmcnt + barrier
  for (int t = 0; t < 8; ++t) {
    int cur = t & 1;
    if (t + 1 < 8) stage(cur ^ 1, (t + 1) << 5);   // prefetch next tile
    const int arow = wr * 64 + l15;
    const int brow = wc * 32 + l15;
    const int kb = g << 3;
    short8 af[4], bq[2], bk[2], bv[2];
#pragma unroll
    for (int m = 0; m < 4; ++m)
      af[m] = *(const short8*)&As[cur][(arow + m * 16) * 32 + kb];
#pragma unroll
    for (int n = 0; n < 2; ++n) {
      bq[n] = *(const short8*)&Bqs[cur][(brow + n * 16) * 32 + kb];
      bk[n] = *(const short8*)&Bks[cur][(brow + n * 16) * 32 + kb];
      bv[n] = *(const short8*)&Bvs[cur][(brow + n * 16) * 32 + kb];
    }
#pragma unroll
    for (int m = 0; m < 4; ++m)
#pragma unroll
      for (int n = 0; n < 2; ++n) {
        acc[0][m][n] = __builtin_amdgcn_mfma_f32_16x16x32_bf16(af[m], bq[n], acc[0][m][n], 0, 0, 0);
        acc[1][m][n] = __builtin_amdgcn_mfma_f32_16x16x32_bf16(af[m], bk[n], acc[1][m][n], 0, 0, 0);
        acc[2][m][n] = __builtin_amdgcn_mfma_f32_16x16x32_bf16(af[m], bv[n], acc[2][m][n], 0, 0, 0);
      }
    __syncthreads();                            // drains prefetch + read fence
  }
  const int cgrp = bn * 2 + wc;                 // (col >> 5) of per-head layout
  const int crow0 = bm + wr * 64 + (g << 2);
#pragma unroll
  for (int m = 0; m < 4; ++m) {
#pragma unroll
    for (int j = 0; j < 4; ++j) {
      int row = crow0 + m * 16 + j;
      size_t hb = ((size_t)((row >> 9) * 8 + cgrp) * 512 + (row & 511)) * 32;
#pragma unroll
      for (int n = 0; n < 2; ++n) {
        int cc = n * 16 + l15;
        qo[hb + cc] = f2bf(acc[0][m][n][j]);
        ko[hb + cc] = f2bf(acc[1][m][n][j]);
        vo[hb + cc] = f2bf(acc[2][m][n][j]);
      }
    }
  }
}

// ------------------------------------------------------------- bf16 MFMA GEMM
// BM=64 x BN=128; 1D grid, XCD-swizzled; 2-phase double-buffered staging.
// mode 0: fp32 row-major (+res). mode 3: bf16 row-major.
// mode 4: packed-bf16 atomic segment-scatter into bf16 sums.
__global__ __launch_bounds__(256) void gemm_bf16(
    const unsigned short* __restrict__ A, const unsigned short* __restrict__ B,
    void* __restrict__ Cv, const float* __restrict__ res,
    const int* __restrict__ seg_index, const int* __restrict__ seg_r2f,
    int M, int N, int K, int mode)
{
  __shared__ unsigned short As[2][64 * 32];
  __shared__ unsigned short Bs[2][128 * 32];
  const int tid = threadIdx.x;
  const int lane = tid & 63, w = tid >> 6;
  const int l15 = lane & 15, g = lane >> 4;
  const int L = xcd_logical(blockIdx.x, gridDim.x);
  const int bn = (L & 1) * 128;
  const int bm = (L >> 1) * 64;
  floatx4 acc[4][2] = {};
  const int sr = (lane >> 2);
  const int sk = (lane & 3) << 3;

  auto stage = [&](int buf, int k0) {
    {                                           // 4 A stripes, 1/wave
      const unsigned short* ga = A + (size_t)(bm + w * 16 + sr) * K + k0 + sk;
      __builtin_amdgcn_global_load_lds(
          (const __attribute__((address_space(1))) void*)ga,
          (__attribute__((address_space(3))) void*)&As[buf][w * 512], 16, 0, 0);
    }
#pragma unroll
    for (int c = 0; c < 2; ++c) {               // 8 B stripes, 2/wave
      int stripe = w * 2 + c;
      const unsigned short* gb = B + (size_t)(bn + stripe * 16 + sr) * K + k0 + sk;
      __builtin_amdgcn_global_load_lds(
          (const __attribute__((address_space(1))) void*)gb,
          (__attribute__((address_space(3))) void*)&Bs[buf][stripe * 512], 16, 0, 0);
    }
  };

  const int nt = K >> 5;
  stage(0, 0);
  __syncthreads();
  for (int t = 0; t < nt; ++t) {
    int cur = t & 1;
    if (t + 1 < nt) stage(cur ^ 1, (t + 1) << 5);
    const int kb = g << 3;
    short8 af[4], bfr[2];
#pragma unroll
    for (int m = 0; m < 4; ++m)
      af[m] = *(const short8*)&As[cur][(m * 16 + l15) * 32 + kb];
#pragma unroll
    for (int n = 0; n < 2; ++n)
      bfr[n] = *(const short8*)&Bs[cur][(w * 32 + n * 16 + l15) * 32 + kb];
#pragma unroll
    for (int m = 0; m < 4; ++m)
#pragma unroll
      for (int n = 0; n < 2; ++n)
        acc[m][n] = __builtin_amdgcn_mfma_f32_16x16x32_bf16(
            af[m], bfr[n], acc[m][n], 0, 0, 0);
    __syncthreads();
  }
  const int crow0 = bm + (g << 2);
  const int ccol0 = bn + w * 32 + l15;
#pragma unroll
  for (int m = 0; m < 4; ++m) {
#pragma unroll
    for (int j = 0; j < 4; ++j) {
      int row = crow0 + m * 16 + j;
      if (row >= M) continue;
      if (mode == 0) {
        float* C = (float*)Cv;
        size_t off = (size_t)row * N + ccol0;
#pragma unroll
        for (int n = 0; n < 2; ++n) {
          float v = acc[m][n][j];
          if (res) v += res[off + n * 16];
          C[off + n * 16] = v;
        }
      } else if (mode == 3) {
        unsigned short* C = (unsigned short*)Cv;
        size_t off = (size_t)row * N + ccol0;
#pragma unroll
        for (int n = 0; n < 2; ++n) C[off + n * 16] = f2bf(acc[m][n][j]);
      } else {  // mode 4: pk bf16 atomic scatter (wave spans 32 cols)
        unsigned short* S = (unsigned short*)Cv;
        int s = seg_index[seg_r2f[row]];
        int gbase = lane & 48;                 // g*16 (row-group origin)
        int le = (2 * l15) & 15;               // src l15 for even col
        int lo = (2 * l15 + 1) & 15;           // src l15 for odd col
        bool hi = (l15 >= 8);
        float va = acc[m][0][j];               // cols base + 0..15
        float vb = acc[m][1][j];               // cols base + 16..31
        float ae = __shfl(va, gbase + le, 64);
        float be = __shfl(vb, gbase + le, 64);
        float ao = __shfl(va, gbase + lo, 64);
        float bo = __shfl(vb, gbase + lo, 64);
        float ev = hi ? be : ae;               // col base + 2*l15
        float ov = hi ? bo : ao;               // col base + 2*l15 + 1
        unsigned pair = (unsigned)f2bf(ev) | ((unsigned)f2bf(ov) << 16);
        unsigned short* addr =
            S + (size_t)s * N + (bn + w * 32) + 2 * l15;
        asm volatile("global_atomic_pk_add_bf16 %0, %1, off"
                     :: "v"(addr), "v"(pair) : "memory");
      }
    }
  }
  if (mode == 4) asm volatile("s_waitcnt vmcnt(0)");  // drain asm atomics
}

// ------------------------------- RoPE in-place on bf16 per-head rows, q AND k
__global__ __launch_bounds__(256) void rope_qk_kernel(
    unsigned short* __restrict__ qb, unsigned short* __restrict__ kb,
    const float* __restrict__ pos, const int* __restrict__ r2f, float qscale)
{
  int row = blockIdx.x * 256 + threadIdx.x;
  if (row >= NFULL_N * HEADS) return;
  int e = row >> 12, p = row & 511;
  int j = (e << 9) | p;
  int pi = r2f[j];
  float pf[3];
  pf[0] = (pos[pi * 3 + 0] + 10.0f) * (1.0f / 35.0f);
  pf[1] = (pos[pi * 3 + 1] + 1.0f)  * (1.0f / 6.0f);
  pf[2] =  pos[pi * 3 + 2] * 0.5f;
  const float invts[5] = {1.0f, 0.3981071706f, 0.1584893192f,
                          0.0630957344f, 0.0251188643f};
  float sn[15], cs[15];
#pragma unroll
  for (int i = 0; i < 3; ++i)
#pragma unroll
    for (int t = 0; t < 5; ++t) {
      float theta = pf[i] * invts[t];
      sn[i * 5 + t] = sinf(theta);
      cs[i * 5 + t] = cosf(theta);
    }
  unsigned short* qr = qb + (size_t)row * 32;
  unsigned short* kr = kb + (size_t)row * 32;
  uint4 qraw[4], kraw[4];
#pragma unroll
  for (int u = 0; u < 4; ++u) { qraw[u] = *(const uint4*)&qr[u * 8];
                                kraw[u] = *(const uint4*)&kr[u * 8]; }
  float q[32], k[32];
  const unsigned short* qs = (const unsigned short*)qraw;
  const unsigned short* ks = (const unsigned short*)kraw;
#pragma unroll
  for (int d = 0; d < 32; ++d) { q[d] = bf2f(qs[d]); k[d] = bf2f(ks[d]); }
#pragma unroll
  for (int i = 0; i < 3; ++i)
#pragma unroll
    for (int t = 0; t < 5; ++t) {
      int fo = i * 10 + t, so = fo + 5, ti = i * 5 + t;
      float c0 = cs[ti], s0 = sn[ti];
      float qf = q[fo], qq = q[so];
      q[fo] = qf * c0 - qq * s0;
      q[so] = qq * c0 + qf * s0;
      float kf = k[fo], kk = k[so];
      k[fo] = kf * c0 - kk * s0;
      k[so] = kk * c0 + kf * s0;
    }
  q[30] = 0.f; q[31] = 0.f; k[30] = 0.f; k[31] = 0.f;
  unsigned qo[16], ko[16];
#pragma unroll
  for (int u = 0; u < 16; ++u) {
    qo[u] = f2bf(q[2*u] * qscale) | ((unsigned)f2bf(q[2*u+1] * qscale) << 16);
    ko[u] = f2bf(k[2*u]) | ((unsigned)f2bf(k[2*u+1]) << 16);
  }
#pragma unroll
  for (int u = 0; u < 4; ++u) {
    *(uint4*)&qr[u * 8] = make_uint4(qo[4*u], qo[4*u+1], qo[4*u+2], qo[4*u+3]);
    *(uint4*)&kr[u * 8] = make_uint4(ko[4*u], ko[4*u+1], ko[4*u+2], ko[4*u+3]);
  }
}

// ------------------------------------------------------------- MFMA attention
__global__ __launch_bounds__(512, 4) void attn_mfma_kernel(
    const unsigned short* __restrict__ qh, const unsigned short* __restrict__ kh,
    const unsigned short* __restrict__ vh, unsigned short* __restrict__ ob)
{
  __shared__ unsigned short K_lds[256 * 40];   // rows padded 32->40 bf16
  __shared__ unsigned short V_lds[32 * 264];   // [d][key] transposed, pad 264
  const int blk = blockIdx.x;
  const int e = blk >> 3, head = blk & 7;
  const int tid = threadIdx.x;
  const int w = tid >> 6, lane = tid & 63;
  const int l15 = lane & 15, g = lane >> 4;
  const size_t rowbase = (size_t)blk * 512;

  short8 qfrag[4];
#pragma unroll
  for (int qt = 0; qt < 4; ++qt) {
    size_t qrow = rowbase + w * 64 + qt * 16 + l15;
    qfrag[qt] = *(const short8*)&qh[qrow * 32 + g * 8];
  }
  floatx4 oacc[4][2] = {};
  floatx4 accl[4] = {};                   // lsum accumulators (ones-MFMA)
  const short one_bf = (short)0x3F80;     // bf16 1.0
  const short8 ones8 = {one_bf, one_bf, one_bf, one_bf,
                        one_bf, one_bf, one_bf, one_bf};
  const float C2 = 28.853900817779268f;  // 20 * log2(e)
  const floatx4 mc2 = {-C2, -C2, -C2, -C2};

  for (int stage = 0; stage < 2; ++stage) {
    const int kc0 = stage * 256;
    __syncthreads();
    // ---- K stage: plain loads, 2 threads/row, padded [256][40]
    {
      const unsigned short* khp = kh + (rowbase + kc0) * 32;
      int r = tid >> 1, half = tid & 1;
      uint4 a = *(const uint4*)&khp[(size_t)r * 32 + half * 16];
      uint4 b = *(const uint4*)&khp[(size_t)r * 32 + half * 16 + 8];
      *(uint4*)&K_lds[r * 40 + half * 16]     = a;
      *(uint4*)&K_lds[r * 40 + half * 16 + 8] = b;
    }
    // ---- V stage: bf16 rows -> transposed [d][key], column-permuted
    {
      int key = tid >> 1, dq = tid & 1;
      const unsigned short* vrow = vh + (rowbase + kc0 + key) * 32 + dq * 16;
      unsigned short tmp[16];
      *(uint4*)&tmp[0] = *(const uint4*)vrow;
      *(uint4*)&tmp[8] = *(const uint4*)(vrow + 8);
      int lam = key & 31;
      int pc = ((lam & 15) >> 2) * 8 + (lam & 3) + ((lam >> 4) << 2);
      int ccol = (key & ~31) + pc;
#pragma unroll
      for (int d = 0; d < 16; ++d)
        V_lds[(dq * 16 + d) * 264 + ccol] = tmp[d];
    }
    __syncthreads();
    // ---- compute: 8 chunks of 32 keys (setprio favors MFMA-phase waves)
    for (int c = 0; c < 8; ++c) {
      short8 kf0 = *(const short8*)&K_lds[(c * 32 + l15) * 40 + g * 8];
      short8 kf1 = *(const short8*)&K_lds[(c * 32 + 16 + l15) * 40 + g * 8];
      short8 vf0 = *(const short8*)&V_lds[l15 * 264 + c * 32 + g * 8];
      short8 vf1 = *(const short8*)&V_lds[(16 + l15) * 264 + c * 32 + g * 8];
      __builtin_amdgcn_s_setprio(1);
#pragma unroll
      for (int qt = 0; qt < 4; ++qt) {
        floatx4 s0 = __builtin_amdgcn_mfma_f32_16x16x32_bf16(kf0, qfrag[qt], mc2, 0, 0, 0);
        floatx4 s1 = __builtin_amdgcn_mfma_f32_16x16x32_bf16(kf1, qfrag[qt], mc2, 0, 0, 0);
        float p0 = fast_exp2(s0[0]), p1 = fast_exp2(s0[1]);
        float p2 = fast_exp2(s0[2]), p3 = fast_exp2(s0[3]);
        float p4 = fast_exp2(s1[0]), p5 = fast_exp2(s1[1]);
        float p6 = fast_exp2(s1[2]), p7 = fast_exp2(s1[3]);
        uintx4 uv = {
          __builtin_amdgcn_perm(__builtin_bit_cast(unsigned, p1),
                                __builtin_bit_cast(unsigned, p0), 0x07060302u),
          __builtin_amdgcn_perm(__builtin_bit_cast(unsigned, p3),
                                __builtin_bit_cast(unsigned, p2), 0x07060302u),
          __builtin_amdgcn_perm(__builtin_bit_cast(unsigned, p5),
                                __builtin_bit_cast(unsigned, p4), 0x07060302u),
          __builtin_amdgcn_perm(__builtin_bit_cast(unsigned, p7),
                                __builtin_bit_cast(unsigned, p6), 0x07060302u)};
        short8 ps8 = __builtin_bit_cast(short8, uv);
        oacc[qt][0] = __builtin_amdgcn_mfma_f32_16x16x32_bf16(ps8, vf0, oacc[qt][0], 0, 0, 0);
        oacc[qt][1] = __builtin_amdgcn_mfma_f32_16x16x32_bf16(ps8, vf1, oacc[qt][1], 0, 0, 0);
        accl[qt]    = __builtin_amdgcn_mfma_f32_16x16x32_bf16(ps8, ones8, accl[qt], 0, 0, 0);
      }
      __builtin_amdgcn_s_setprio(0);
    }
  }
  // ---- normalize + store: accl[qt][j] = full lsum for query row g*4+j
  const size_t obase = ((size_t)e * 512) * 256 + head * 32;
#pragma unroll
  for (int qt = 0; qt < 4; ++qt) {
#pragma unroll
    for (int j = 0; j < 4; ++j) {
      float inv = fast_rcp(accl[qt][j]);
      int p = w * 64 + qt * 16 + g * 4 + j;
      size_t off = obase + (size_t)p * 256 + l15;
      ob[off]      = f2bf(oacc[qt][0][j] * inv);
      ob[off + 16] = f2bf(oacc[qt][1][j] * inv);
    }
  }
}

// ---------------------------------- x2 = x + mean[seg-chain]; LN2 fused
// sums is bf16 [NRED][256]
__global__ __launch_bounds__(256) void addmean_ln2_kernel(
    const float* __restrict__ x, const int* __restrict__ index,
    const int* __restrict__ r2f, const int* __restrict__ f2r,
    const unsigned short* __restrict__ sums, const float* __restrict__ cnts,
    const float* __restrict__ w, const float* __restrict__ b,
    float* __restrict__ x2, unsigned short* __restrict__ ln2b)
{
  int wave = threadIdx.x >> 6, lane = threadIdx.x & 63;
  int r = blockIdx.x * 4 + wave;
  if (r >= NRED_N) return;
  int j = f2r[r];
  int s = index[r2f[j]];
  float inv = 1.0f / fmaxf(cnts[s], 1.0f);
  uint2 sr = *(const uint2*)&sums[(size_t)s * C_DIM + (lane << 2)];
  float4 sv = make_float4(bf2f((unsigned short)(sr.x & 0xFFFF)),
                          bf2f((unsigned short)(sr.x >> 16)),
                          bf2f((unsigned short)(sr.y & 0xFFFF)),
                          bf2f((unsigned short)(sr.y >> 16)));
  float4 xv = *(const float4*)&x[(size_t)r * C_DIM + (lane << 2)];
  float4 o = make_float4(xv.x + sv.x * inv, xv.y + sv.y * inv,
                         xv.z + sv.z * inv, xv.w + sv.w * inv);
  *(float4*)&x2[(size_t)r * C_DIM + (lane << 2)] = o;
  // fused LN2
  float ssum = o.x + o.y + o.z + o.w;
  float sq = o.x*o.x + o.y*o.y + o.z*o.z + o.w*o.w;
  ssum = wave_reduce_sum(ssum);
  sq   = wave_reduce_sum(sq);
  float mean = ssum * (1.0f / 256.0f);
  float var  = sq * (1.0f / 256.0f) - mean * mean;
  float rstd = rsqrtf(var + 1e-5f);
  float4 wv = *(const float4*)&w[lane << 2];
  float4 bv = *(const float4*)&b[lane << 2];
  float ox = (o.x - mean) * rstd * wv.x + bv.x;
  float oy = (o.y - mean) * rstd * wv.y + bv.y;
  float oz = (o.z - mean) * rstd * wv.z + bv.z;
  float ow = (o.w - mean) * rstd * wv.w + bv.w;
  unsigned u0 = f2bf(ox) | ((unsigned)f2bf(oy) << 16);
  unsigned u1 = f2bf(oz) | ((unsigned)f2bf(ow) << 16);
  *(uint2*)&ln2b[(size_t)r * C_DIM + (lane << 2)] = make_uint2(u0, u1);
}

// --------------------------------------- FFN1 + gated SiLU fused (bf16 out)
// BM=64; 1D grid 1564, XCD-swizzled; 2-phase double-buffered staging.
__global__ __launch_bounds__(256) void ffn1_act_kernel(
    const unsigned short* __restrict__ A, const unsigned short* __restrict__ B,
    unsigned short* __restrict__ act, int M)
{
  __shared__ unsigned short As[2][64 * 32];
  __shared__ unsigned short Bas[2][128 * 32];
  __shared__ unsigned short Bgs[2][128 * 32];
  const int tid = threadIdx.x;
  const int lane = tid & 63, w = tid >> 6;
  const int l15 = lane & 15, g = lane >> 4;
  const int L = xcd_logical(blockIdx.x, gridDim.x);
  const int bn = L & 1;
  const int bm = (L >> 1) * 64;
  floatx4 acc_a[4][2] = {}, acc_g[4][2] = {};
  const int sr = (lane >> 2);
  const int sk = (lane & 3) << 3;

  auto stage = [&](int buf, int k0) {
    {                                           // 4 A stripes, 1/wave
      const unsigned short* ga = A + (size_t)(bm + w * 16 + sr) * 256 + k0 + sk;
      __builtin_amdgcn_global_load_lds(
          (const __attribute__((address_space(1))) void*)ga,
          (__attribute__((address_space(3))) void*)&As[buf][w * 512], 16, 0, 0);
    }
#pragma unroll
    for (int c = 0; c < 2; ++c) {               // 8 stripes each for Ba, Bg
      int stripe = w * 2 + c;
      const unsigned short* gba = B + (size_t)(bn * 128 + stripe * 16 + sr) * 256 + k0 + sk;
      const unsigned short* gbg = B + (size_t)(256 + bn * 128 + stripe * 16 + sr) * 256 + k0 + sk;
      __builtin_amdgcn_global_load_lds(
          (const __attribute__((address_space(1))) void*)gba,
          (__attribute__((address_space(3))) void*)&Bas[buf][stripe * 512], 16, 0, 0);
      __builtin_amdgcn_global_load_lds(
          (const __attribute__((address_space(1))) void*)gbg,
          (__attribute__((address_space(3))) void*)&Bgs[buf][stripe * 512], 16, 0, 0);
    }
  };

  stage(0, 0);
  __syncthreads();
  for (int t = 0; t < 8; ++t) {
    int cur = t & 1;
    if (t + 1 < 8) stage(cur ^ 1, (t + 1) << 5);
    const int kb = g << 3;
    short8 af[4], ba[2], bg2[2];
#pragma unroll
    for (int m = 0; m < 4; ++m)
      af[m] = *(const short8*)&As[cur][(m * 16 + l15) * 32 + kb];
#pragma unroll
    for (int n = 0; n < 2; ++n) {
      ba[n]  = *(const short8*)&Bas[cur][(w * 32 + n * 16 + l15) * 32 + kb];
      bg2[n] = *(const short8*)&Bgs[cur][(w * 32 + n * 16 + l15) * 32 + kb];
    }
#pragma unroll
    for (int m = 0; m < 4; ++m)
#pragma unroll
      for (int n = 0; n < 2; ++n) {
        acc_a[m][n] = __builtin_amdgcn_mfma_f32_16x16x32_bf16(
            af[m], ba[n], acc_a[m][n], 0, 0, 0);
        acc_g[m][n] = __builtin_amdgcn_mfma_f32_16x16x32_bf16(
            af[m], bg2[n], acc_g[m][n], 0, 0, 0);
      }
    __syncthreads();
  }
  const int crow0 = bm + (g << 2);
  const int ccol0 = bn * 128 + w * 32 + l15;
  const float LOG2E = 1.4426950408889634f;
#pragma unroll
  for (int m = 0; m < 4; ++m) {
#pragma unroll
    for (int j = 0; j < 4; ++j) {
      int row = crow0 + m * 16 + j;
      if (row >= M) continue;
      size_t off = (size_t)row * 256 + ccol0;
#pragma unroll
      for (int n = 0; n < 2; ++n) {
        float a = acc_a[m][n][j];
        float gg = acc_g[m][n][j];
        float eneg = fast_exp2(-gg * LOG2E);
        float v = a * gg * fast_rcp(1.0f + eneg);
        act[off + n * 16] = f2bf(v);
      }
    }
  }
}

// ======================================================================
extern "C" void kernel_launch(void* const* d_in, const int* in_sizes, int n_in,
                              void* d_out, int out_size, void* d_ws, size_t ws_size,
                              hipStream_t stream)
{
  const float* x    = (const float*)d_in[0];
  const float* pos  = (const float*)d_in[1];
  const int*   index= (const int*)d_in[2];
  const int*   r2f  = (const int*)d_in[3];
  const int*   f2r  = (const int*)d_in[4];
  const float* n1w  = (const float*)d_in[5];
  const float* n1b  = (const float*)d_in[6];
  const float* qw   = (const float*)d_in[7];
  const float* kw   = (const float*)d_in[8];
  const float* vw   = (const float*)d_in[9];
  const float* ow   = (const float*)d_in[10];
  const float* n2w  = (const float*)d_in[11];
  const float* n2b  = (const float*)d_in[12];
  const float* w1   = (const float*)d_in[13];
  const float* w2   = (const float*)d_in[14];
  float* out = (float*)d_out;

  // ---- workspace layout (ws = 256 MiB)
  char* ws = (char*)d_ws;
  unsigned short* xnbf = (unsigned short*)(ws);               // [0, 33.5M)
  unsigned short* qhh  = (unsigned short*)(ws + 33554432);    // [33.5M, 67.1M)
  unsigned short* khh  = (unsigned short*)(ws + 67108864);    // [67.1M, 100.7M)
  unsigned short* vhh  = (unsigned short*)(ws + 100663296);   // [100.7M, 134.2M)
  float* x2   = (float*)(ws + 134217728);  // [134.2M, 185.4M)
  float* cnts = (float*)(ws + 185417728);  // 0.2MB
  unsigned short* wbf = (unsigned short*)(ws + 185617728);    // 0.98MB
  unsigned short* sums = (unsigned short*)(ws + 186646528);   // bf16, 25.6MB
  unsigned short* qwb = wbf;
  unsigned short* kwb = wbf + 65536;
  unsigned short* vwb = wbf + 2 * 65536;
  unsigned short* owb = wbf + 3 * 65536;
  unsigned short* w1b = wbf + 4 * 65536;   // 131072 elems
  unsigned short* w2b = wbf + 6 * 65536;
  // aliases (lifetimes):
  unsigned short* attn_out = xnbf;  // xnbf dead after QKV
  unsigned short* ln2b = xnbf;      // attn_out dead after O-proj
  unsigned short* actb = qhh;       // qhh dead after attention

  // 0. zero-init atomic targets and weight cvt
  hipMemsetAsync(sums, 0, (size_t)NRED_N * C_DIM * 2, stream);
  hipMemsetAsync(cnts, 0, (size_t)NRED_N * 4, stream);
  cvt_all_kernel<<<448, 256, 0, stream>>>(qw, kw, vw, ow, w1, w2,
                                          qwb, kwb, vwb, owb, w1b, w2b);
  // 1. gather + LN1 (+ fused segment count)
  ln_kernel<<<NFULL_N / 4, 256, 0, stream>>>(x, r2f, n1w, n1b, xnbf, NFULL_N,
                                             index, cnts);
  // 2. fused QKV projection -> per-head bf16 (XCD-swizzled, double-buffered)
  qkv_kernel<<<2048, 256, 0, stream>>>(xnbf, qwb, kwb, vwb, qhh, khh, vhh);
  // 3. fused RoPE on q,k (q pre-scaled by C1)
  const float C1 = 0.26339891f;   // (1/sqrt(30)) * log2(e)
  rope_qk_kernel<<<NFULL_N * HEADS / 256, 256, 0, stream>>>(qhh, khh, pos, r2f, C1);
  // 4. MFMA attention -> attn_out bf16 [65536][256]
  attn_mfma_kernel<<<NE_N * HEADS, 512, 0, stream>>>(qhh, khh, vhh, attn_out);
  // 5+6. O projection fused with packed-bf16 segment scatter (mode 4)
  gemm_bf16<<<2048, 256, 0, stream>>>(attn_out, owb, sums, nullptr,
                                      index, r2f, NFULL_N, C_DIM, C_DIM, 4);
  // 7-8. x2 = x + gathered mean; LN2 fused (bf16 sums in)
  addmean_ln2_kernel<<<(NRED_N + 3) / 4, 256, 0, stream>>>(
      x, index, r2f, f2r, sums, cnts, n2w, n2b, x2, ln2b);
  // 9-10. FFN1 + gated SiLU fused (bf16 out)
  ffn1_act_kernel<<<1564, 256, 0, stream>>>(ln2b, w1b, actb, NRED_N);
  // 11. FFN2 + residual -> out
  gemm_bf16<<<1564, 256, 0, stream>>>(actb, w2b, out, x2,
                                      nullptr, nullptr, NRED_N, C_DIM, C_DIM, 0);
}

// Round 17
// 341.915 us; speedup vs baseline: 1.0674x; 1.0674x over previous
//
#include <hip/hip_runtime.h>
#include <hip/hip_bf16.h>
#include <cstddef>

#define C_DIM 256
#define HEADS 8
#define HD 32
#define NPTS 512
#define NFULL_N 65536
#define NRED_N 50000
#define NE_N 128

typedef __attribute__((ext_vector_type(8))) short short8;
typedef __attribute__((ext_vector_type(4))) float floatx4;
typedef __attribute__((ext_vector_type(4))) unsigned uintx4;

// ---------------------------------------------------------------- utilities
__device__ __forceinline__ float wave_reduce_sum(float v) {
#pragma unroll
  for (int off = 1; off < 64; off <<= 1) v += __shfl_xor(v, off, 64);
  return v;
}

__device__ __forceinline__ unsigned short f2bf(float f) {
  union { float f; unsigned u; } x; x.f = f;
  unsigned r = x.u + 0x7FFF + ((x.u >> 16) & 1);   // round-to-nearest-even
  return (unsigned short)(r >> 16);
}

__device__ __forceinline__ float bf2f(unsigned short u) {
  union { unsigned u; float f; } x; x.u = ((unsigned)u) << 16;
  return x.f;
}

__device__ __forceinline__ float fast_exp2(float x) {
#if __has_builtin(__builtin_amdgcn_exp2f)
  return __builtin_amdgcn_exp2f(x);
#else
  return exp2f(x);
#endif
}

__device__ __forceinline__ float fast_rcp(float x) {
#if __has_builtin(__builtin_amdgcn_rcpf)
  return __builtin_amdgcn_rcpf(x);
#else
  return 1.0f / x;
#endif
}

// XCD-aware bijective block remap: dispatch id -> logical id such that each
// XCD (hw: id % 8) owns a CONTIGUOUS logical range (per-XCD L2 reuse).
__device__ __forceinline__ int xcd_logical(int bid, int nwg) {
  int q = nwg >> 3, r = nwg & 7;
  int xcd = bid & 7, s = bid >> 3;
  int base = (xcd < r) ? xcd * (q + 1) : r * (q + 1) + (xcd - r) * q;
  return base + s;
}

// --------------------------------------------- all weights fp32 -> bf16, 1 launch
__global__ __launch_bounds__(256) void cvt_all_kernel(
    const float* __restrict__ qw, const float* __restrict__ kw,
    const float* __restrict__ vw, const float* __restrict__ ow,
    const float* __restrict__ w1, const float* __restrict__ w2,
    unsigned short* __restrict__ qwb, unsigned short* __restrict__ kwb,
    unsigned short* __restrict__ vwb, unsigned short* __restrict__ owb,
    unsigned short* __restrict__ w1b, unsigned short* __restrict__ w2b)
{
  int i = blockIdx.x * 256 + threadIdx.x;          // float4 index, total 114688
  const float* src; unsigned short* dst; int o;
  if      (i <  16384) { src = qw; dst = qwb; o = i; }
  else if (i <  32768) { src = kw; dst = kwb; o = i - 16384; }
  else if (i <  49152) { src = vw; dst = vwb; o = i - 32768; }
  else if (i <  65536) { src = ow; dst = owb; o = i - 49152; }
  else if (i <  98304) { src = w1; dst = w1b; o = i - 65536; }
  else                 { src = w2; dst = w2b; o = i - 98304; }
  float4 v = *(const float4*)&src[o << 2];
  unsigned u0 = f2bf(v.x) | ((unsigned)f2bf(v.y) << 16);
  unsigned u1 = f2bf(v.z) | ((unsigned)f2bf(v.w) << 16);
  *(uint2*)&dst[o << 2] = make_uint2(u0, u1);
}

// ------------------------- LayerNorm1 (gather, bf16 out) + fused segment cnt
__global__ __launch_bounds__(256) void ln_kernel(
    const float* __restrict__ x, const int* __restrict__ gidx,
    const float* __restrict__ w, const float* __restrict__ b,
    unsigned short* __restrict__ out, int nrows,
    const int* __restrict__ index, float* __restrict__ cnts)
{
  int wave = threadIdx.x >> 6, lane = threadIdx.x & 63;
  int row = blockIdx.x * 4 + wave;
  if (row >= nrows) return;
  int src = gidx ? gidx[row] : row;
  if (cnts && lane == 0) atomicAdd(&cnts[index[src]], 1.0f);
  const float* xr = x + (size_t)src * C_DIM;
  float4 v = *(const float4*)&xr[lane << 2];
  float s  = v.x + v.y + v.z + v.w;
  float sq = v.x*v.x + v.y*v.y + v.z*v.z + v.w*v.w;
  s  = wave_reduce_sum(s);
  sq = wave_reduce_sum(sq);
  float mean = s * (1.0f / 256.0f);
  float var  = sq * (1.0f / 256.0f) - mean * mean;
  float rstd = rsqrtf(var + 1e-5f);
  float4 wv = *(const float4*)&w[lane << 2];
  float4 bv = *(const float4*)&b[lane << 2];
  float ox = (v.x - mean) * rstd * wv.x + bv.x;
  float oy = (v.y - mean) * rstd * wv.y + bv.y;
  float oz = (v.z - mean) * rstd * wv.z + bv.z;
  float ow = (v.w - mean) * rstd * wv.w + bv.w;
  unsigned u0 = f2bf(ox) | ((unsigned)f2bf(oy) << 16);
  unsigned u1 = f2bf(oz) | ((unsigned)f2bf(ow) << 16);
  *(uint2*)&out[(size_t)row * C_DIM + (lane << 2)] = make_uint2(u0, u1);
}

// ---------------------------------------- fused QKV projection + RoPE epilogue
// 1D grid 2048, XCD-swizzled: bn = L&3 (fastest), bm = L>>2. Single-buffered.
// Epilogue: V written direct; Q/K staged through a swizzled LDS tile so each
// thread owns one full head-row -> rope in-register -> 64B contiguous write.
__global__ __launch_bounds__(256) void qkv_kernel(
    const unsigned short* __restrict__ A,
    const unsigned short* __restrict__ Bq, const unsigned short* __restrict__ Bk,
    const unsigned short* __restrict__ Bv,
    const float* __restrict__ pos, const int* __restrict__ r2f,
    unsigned short* __restrict__ qo, unsigned short* __restrict__ ko,
    unsigned short* __restrict__ vo, float qscale)
{
  __shared__ unsigned short As[128 * 32];
  __shared__ unsigned short Bqs[64 * 32];
  __shared__ unsigned short Bks[64 * 32];
  __shared__ unsigned short Bvs[64 * 32];
  __shared__ unsigned short Tile[128 * 64];   // 16KB rope-staging tile
  const int tid = threadIdx.x;
  const int lane = tid & 63, w = tid >> 6;
  const int wr = w >> 1, wc = w & 1;
  const int l15 = lane & 15, g = lane >> 4;
  const int L = xcd_logical(blockIdx.x, 2048);
  const int bn = L & 3;                     // 64-col slice (fastest)
  const int bm = (L >> 2) * 128;
  floatx4 acc[3][4][2] = {};
  const int sr = lane >> 2;
  const int sk = (lane & 3) << 3;
  for (int k0 = 0; k0 < 256; k0 += 32) {
#pragma unroll
    for (int c = 0; c < 2; ++c) {               // 8 A stripes, 2/wave
      int stripe = w * 2 + c;
      const unsigned short* ga = A + (size_t)(bm + stripe * 16 + sr) * 256 + k0 + sk;
      __builtin_amdgcn_global_load_lds(
          (const __attribute__((address_space(1))) void*)ga,
          (__attribute__((address_space(3))) void*)&As[stripe * 512], 16, 0, 0);
    }
#pragma unroll
    for (int c = 0; c < 3; ++c) {               // 12 B stripes, 3/wave
      int idx = w * 3 + c;                      // 0..11
      int t = idx >> 2, rs = idx & 3;
      const unsigned short* Bt = (t == 0) ? Bq : (t == 1) ? Bk : Bv;
      unsigned short* ldst = (t == 0) ? &Bqs[rs * 512]
                           : (t == 1) ? &Bks[rs * 512] : &Bvs[rs * 512];
      const unsigned short* gsrc = Bt + (size_t)(bn * 64 + rs * 16 + sr) * 256 + k0 + sk;
      __builtin_amdgcn_global_load_lds(
          (const __attribute__((address_space(1))) void*)gsrc,
          (__attribute__((address_space(3))) void*)ldst, 16, 0, 0);
    }
    __syncthreads();
    const int arow = wr * 64 + l15;
    const int brow = wc * 32 + l15;
    const int kb = g << 3;
    short8 af[4], bq[2], bk[2], bv[2];
#pragma unroll
    for (int m = 0; m < 4; ++m)
      af[m] = *(const short8*)&As[(arow + m * 16) * 32 + kb];
#pragma unroll
    for (int n = 0; n < 2; ++n) {
      bq[n] = *(const short8*)&Bqs[(brow + n * 16) * 32 + kb];
      bk[n] = *(const short8*)&Bks[(brow + n * 16) * 32 + kb];
      bv[n] = *(const short8*)&Bvs[(brow + n * 16) * 32 + kb];
    }
#pragma unroll
    for (int m = 0; m < 4; ++m)
#pragma unroll
      for (int n = 0; n < 2; ++n) {
        acc[0][m][n] = __builtin_amdgcn_mfma_f32_16x16x32_bf16(af[m], bq[n], acc[0][m][n], 0, 0, 0);
        acc[1][m][n] = __builtin_amdgcn_mfma_f32_16x16x32_bf16(af[m], bk[n], acc[1][m][n], 0, 0, 0);
        acc[2][m][n] = __builtin_amdgcn_mfma_f32_16x16x32_bf16(af[m], bv[n], acc[2][m][n], 0, 0, 0);
      }
    __syncthreads();
  }
  // ---- V: direct per-head write from acc[2]
  const int cgrp0 = bn * 2 + wc;
  const int crow0 = bm + wr * 64 + (g << 2);
#pragma unroll
  for (int m = 0; m < 4; ++m) {
#pragma unroll
    for (int j = 0; j < 4; ++j) {
      int row = crow0 + m * 16 + j;
      size_t hb = ((size_t)((row >> 9) * 8 + cgrp0) * 512 + (row & 511)) * 32;
#pragma unroll
      for (int n = 0; n < 2; ++n)
        vo[hb + n * 16 + l15] = f2bf(acc[2][m][n][j]);
    }
  }
  // ---- Q,K: tile -> LDS (swizzled) -> per-thread head-row rope -> write
  const int rr = tid & 127;                   // tile row this thread owns
  const int half = tid >> 7;                  // 32-col head chunk
  const int jrow = bm + rr;                   // global point row
  const int pi = r2f[jrow];
  float pf[3];
  pf[0] = (pos[pi * 3 + 0] + 10.0f) * (1.0f / 35.0f);
  pf[1] = (pos[pi * 3 + 1] + 1.0f)  * (1.0f / 6.0f);
  pf[2] =  pos[pi * 3 + 2] * 0.5f;
  const size_t hbw = ((size_t)((jrow >> 9) * 8 + bn * 2 + half) * 512 +
                      (jrow & 511)) * 32;
  const int rst = wr * 64 + (g << 2);         // store-side row base
  const float invts[5] = {1.0f, 0.3981071706f, 0.1584893192f,
                          0.0630957344f, 0.0251188643f};
#pragma unroll
  for (int tq = 0; tq < 2; ++tq) {
    __syncthreads();                          // tile free (prev pass read done)
#pragma unroll
    for (int m = 0; m < 4; ++m)
#pragma unroll
      for (int j = 0; j < 4; ++j) {
        int r0 = rst + m * 16 + j;
#pragma unroll
        for (int n = 0; n < 2; ++n) {
          int idx = r0 * 64 + wc * 32 + n * 16 + l15;
          Tile[idx ^ ((r0 & 7) << 3)] = f2bf(acc[tq][m][n][j]);
        }
      }
    __syncthreads();
    float qv[32];
    int base = rr * 64 + half * 32;
    int swz = (rr & 7) << 3;
#pragma unroll
    for (int u = 0; u < 4; ++u) {
      uint4 raw = *(const uint4*)&Tile[(base + u * 8) ^ swz];
      const unsigned short* rs2 = (const unsigned short*)&raw;
#pragma unroll
      for (int d = 0; d < 8; ++d) qv[u * 8 + d] = bf2f(rs2[d]);
    }
#pragma unroll
    for (int i = 0; i < 3; ++i)
#pragma unroll
      for (int t5 = 0; t5 < 5; ++t5) {
        float theta = pf[i] * invts[t5];
        float sn = sinf(theta), cst = cosf(theta);
        int fo = i * 10 + t5, so = fo + 5;
        float a = qv[fo], b2 = qv[so];
        qv[fo] = a * cst - b2 * sn;
        qv[so] = b2 * cst + a * sn;
      }
    qv[30] = 0.f; qv[31] = 0.f;
    float scl = (tq == 0) ? qscale : 1.0f;
    unsigned po[16];
#pragma unroll
    for (int u = 0; u < 16; ++u)
      po[u] = f2bf(qv[2*u] * scl) | ((unsigned)f2bf(qv[2*u+1] * scl) << 16);
    unsigned short* dst = (tq == 0 ? qo : ko) + hbw;
#pragma unroll
    for (int u = 0; u < 4; ++u)
      *(uint4*)&dst[u * 8] = make_uint4(po[4*u], po[4*u+1], po[4*u+2], po[4*u+3]);
  }
}

// ------------------------------------------------------------- bf16 MFMA GEMM
// BM=64 x BN=128; 1D grid, XCD-swizzled: bn = L&1 (fastest), bm = L>>1.
// mode 0: fp32 row-major (+res). mode 3: bf16 row-major.
// mode 4: packed-bf16 atomic segment-scatter into bf16 sums.
__global__ __launch_bounds__(256) void gemm_bf16(
    const unsigned short* __restrict__ A, const unsigned short* __restrict__ B,
    void* __restrict__ Cv, const float* __restrict__ res,
    const int* __restrict__ seg_index, const int* __restrict__ seg_r2f,
    int M, int N, int K, int mode)
{
  __shared__ unsigned short As[64 * 32];
  __shared__ unsigned short Bs[128 * 32];
  const int tid = threadIdx.x;
  const int lane = tid & 63, w = tid >> 6;
  const int l15 = lane & 15, g = lane >> 4;
  const int L = xcd_logical(blockIdx.x, gridDim.x);
  const int bn = (L & 1) * 128;
  const int bm = (L >> 1) * 64;
  floatx4 acc[4][2] = {};
  const int sr = (lane >> 2);
  const int sk = (lane & 3) << 3;
  for (int k0 = 0; k0 < K; k0 += 32) {
    {                                           // 4 A stripes, 1/wave
      const unsigned short* ga = A + (size_t)(bm + w * 16 + sr) * K + k0 + sk;
      __builtin_amdgcn_global_load_lds(
          (const __attribute__((address_space(1))) void*)ga,
          (__attribute__((address_space(3))) void*)&As[w * 512], 16, 0, 0);
    }
#pragma unroll
    for (int c = 0; c < 2; ++c) {               // 8 B stripes, 2/wave
      int stripe = w * 2 + c;
      const unsigned short* gb = B + (size_t)(bn + stripe * 16 + sr) * K + k0 + sk;
      __builtin_amdgcn_global_load_lds(
          (const __attribute__((address_space(1))) void*)gb,
          (__attribute__((address_space(3))) void*)&Bs[stripe * 512], 16, 0, 0);
    }
    __syncthreads();
    const int kb = g << 3;
    short8 af[4], bfr[2];
#pragma unroll
    for (int m = 0; m < 4; ++m)
      af[m] = *(const short8*)&As[(m * 16 + l15) * 32 + kb];
#pragma unroll
    for (int n = 0; n < 2; ++n)
      bfr[n] = *(const short8*)&Bs[(w * 32 + n * 16 + l15) * 32 + kb];
#pragma unroll
    for (int m = 0; m < 4; ++m)
#pragma unroll
      for (int n = 0; n < 2; ++n)
        acc[m][n] = __builtin_amdgcn_mfma_f32_16x16x32_bf16(
            af[m], bfr[n], acc[m][n], 0, 0, 0);
    __syncthreads();
  }
  const int crow0 = bm + (g << 2);
  const int ccol0 = bn + w * 32 + l15;
#pragma unroll
  for (int m = 0; m < 4; ++m) {
#pragma unroll
    for (int j = 0; j < 4; ++j) {
      int row = crow0 + m * 16 + j;
      if (row >= M) continue;
      if (mode == 0) {
        float* C = (float*)Cv;
        size_t off = (size_t)row * N + ccol0;
#pragma unroll
        for (int n = 0; n < 2; ++n) {
          float v = acc[m][n][j];
          if (res) v += res[off + n * 16];
          C[off + n * 16] = v;
        }
      } else if (mode == 3) {
        unsigned short* C = (unsigned short*)Cv;
        size_t off = (size_t)row * N + ccol0;
#pragma unroll
        for (int n = 0; n < 2; ++n) C[off + n * 16] = f2bf(acc[m][n][j]);
      } else {  // mode 4: pk bf16 atomic scatter (wave spans 32 cols)
        unsigned short* S = (unsigned short*)Cv;
        int s = seg_index[seg_r2f[row]];
        int gbase = lane & 48;                 // g*16 (row-group origin)
        int le = (2 * l15) & 15;               // src l15 for even col
        int lo = (2 * l15 + 1) & 15;           // src l15 for odd col
        bool hi = (l15 >= 8);
        float va = acc[m][0][j];               // cols base + 0..15
        float vb = acc[m][1][j];               // cols base + 16..31
        float ae = __shfl(va, gbase + le, 64);
        float be = __shfl(vb, gbase + le, 64);
        float ao = __shfl(va, gbase + lo, 64);
        float bo = __shfl(vb, gbase + lo, 64);
        float ev = hi ? be : ae;               // col base + 2*l15
        float ov = hi ? bo : ao;               // col base + 2*l15 + 1
        unsigned pair = (unsigned)f2bf(ev) | ((unsigned)f2bf(ov) << 16);
        unsigned short* addr =
            S + (size_t)s * N + (bn + w * 32) + 2 * l15;
        asm volatile("global_atomic_pk_add_bf16 %0, %1, off"
                     :: "v"(addr), "v"(pair) : "memory");
      }
    }
  }
  if (mode == 4) asm volatile("s_waitcnt vmcnt(0)");  // drain asm atomics
}

// ------------------------------------------------------------- MFMA attention
__global__ __launch_bounds__(512, 4) void attn_mfma_kernel(
    const unsigned short* __restrict__ qh, const unsigned short* __restrict__ kh,
    const unsigned short* __restrict__ vh, unsigned short* __restrict__ ob)
{
  __shared__ unsigned short K_lds[256 * 40];   // rows padded 32->40 bf16
  __shared__ unsigned short V_lds[32 * 264];   // [d][key] transposed, pad 264
  const int blk = blockIdx.x;
  const int e = blk >> 3, head = blk & 7;
  const int tid = threadIdx.x;
  const int w = tid >> 6, lane = tid & 63;
  const int l15 = lane & 15, g = lane >> 4;
  const size_t rowbase = (size_t)blk * 512;

  short8 qfrag[4];
#pragma unroll
  for (int qt = 0; qt < 4; ++qt) {
    size_t qrow = rowbase + w * 64 + qt * 16 + l15;
    qfrag[qt] = *(const short8*)&qh[qrow * 32 + g * 8];
  }
  floatx4 oacc[4][2] = {};
  floatx4 accl[4] = {};                   // lsum accumulators (ones-MFMA)
  const short one_bf = (short)0x3F80;     // bf16 1.0
  const short8 ones8 = {one_bf, one_bf, one_bf, one_bf,
                        one_bf, one_bf, one_bf, one_bf};
  const float C2 = 28.853900817779268f;  // 20 * log2(e)
  const floatx4 mc2 = {-C2, -C2, -C2, -C2};

  for (int stage = 0; stage < 2; ++stage) {
    const int kc0 = stage * 256;
    __syncthreads();
    // ---- K stage: plain loads, 2 threads/row, padded [256][40]
    {
      const unsigned short* khp = kh + (rowbase + kc0) * 32;
      int r = tid >> 1, half = tid & 1;
      uint4 a = *(const uint4*)&khp[(size_t)r * 32 + half * 16];
      uint4 b = *(const uint4*)&khp[(size_t)r * 32 + half * 16 + 8];
      *(uint4*)&K_lds[r * 40 + half * 16]     = a;
      *(uint4*)&K_lds[r * 40 + half * 16 + 8] = b;
    }
    // ---- V stage: bf16 rows -> transposed [d][key], column-permuted
    {
      int key = tid >> 1, dq = tid & 1;
      const unsigned short* vrow = vh + (rowbase + kc0 + key) * 32 + dq * 16;
      unsigned short tmp[16];
      *(uint4*)&tmp[0] = *(const uint4*)vrow;
      *(uint4*)&tmp[8] = *(const uint4*)(vrow + 8);
      int lam = key & 31;
      int pc = ((lam & 15) >> 2) * 8 + (lam & 3) + ((lam >> 4) << 2);
      int ccol = (key & ~31) + pc;
#pragma unroll
      for (int d = 0; d < 16; ++d)
        V_lds[(dq * 16 + d) * 264 + ccol] = tmp[d];
    }
    __syncthreads();
    // ---- compute: 8 chunks of 32 keys (setprio favors MFMA-phase waves)
    for (int c = 0; c < 8; ++c) {
      short8 kf0 = *(const short8*)&K_lds[(c * 32 + l15) * 40 + g * 8];
      short8 kf1 = *(const short8*)&K_lds[(c * 32 + 16 + l15) * 40 + g * 8];
      short8 vf0 = *(const short8*)&V_lds[l15 * 264 + c * 32 + g * 8];
      short8 vf1 = *(const short8*)&V_lds[(16 + l15) * 264 + c * 32 + g * 8];
      __builtin_amdgcn_s_setprio(1);
#pragma unroll
      for (int qt = 0; qt < 4; ++qt) {
        floatx4 s0 = __builtin_amdgcn_mfma_f32_16x16x32_bf16(kf0, qfrag[qt], mc2, 0, 0, 0);
        floatx4 s1 = __builtin_amdgcn_mfma_f32_16x16x32_bf16(kf1, qfrag[qt], mc2, 0, 0, 0);
        float p0 = fast_exp2(s0[0]), p1 = fast_exp2(s0[1]);
        float p2 = fast_exp2(s0[2]), p3 = fast_exp2(s0[3]);
        float p4 = fast_exp2(s1[0]), p5 = fast_exp2(s1[1]);
        float p6 = fast_exp2(s1[2]), p7 = fast_exp2(s1[3]);
        uintx4 uv = {
          __builtin_amdgcn_perm(__builtin_bit_cast(unsigned, p1),
                                __builtin_bit_cast(unsigned, p0), 0x07060302u),
          __builtin_amdgcn_perm(__builtin_bit_cast(unsigned, p3),
                                __builtin_bit_cast(unsigned, p2), 0x07060302u),
          __builtin_amdgcn_perm(__builtin_bit_cast(unsigned, p5),
                                __builtin_bit_cast(unsigned, p4), 0x07060302u),
          __builtin_amdgcn_perm(__builtin_bit_cast(unsigned, p7),
                                __builtin_bit_cast(unsigned, p6), 0x07060302u)};
        short8 ps8 = __builtin_bit_cast(short8, uv);
        oacc[qt][0] = __builtin_amdgcn_mfma_f32_16x16x32_bf16(ps8, vf0, oacc[qt][0], 0, 0, 0);
        oacc[qt][1] = __builtin_amdgcn_mfma_f32_16x16x32_bf16(ps8, vf1, oacc[qt][1], 0, 0, 0);
        accl[qt]    = __builtin_amdgcn_mfma_f32_16x16x32_bf16(ps8, ones8, accl[qt], 0, 0, 0);
      }
      __builtin_amdgcn_s_setprio(0);
    }
  }
  // ---- normalize + store: accl[qt][j] = full lsum for query row g*4+j
  const size_t obase = ((size_t)e * 512) * 256 + head * 32;
#pragma unroll
  for (int qt = 0; qt < 4; ++qt) {
#pragma unroll
    for (int j = 0; j < 4; ++j) {
      float inv = fast_rcp(accl[qt][j]);
      int p = w * 64 + qt * 16 + g * 4 + j;
      size_t off = obase + (size_t)p * 256 + l15;
      ob[off]      = f2bf(oacc[qt][0][j] * inv);
      ob[off + 16] = f2bf(oacc[qt][1][j] * inv);
    }
  }
}

// ---------------------------------- x2 = x + mean[seg-chain]; LN2 fused
// sums is bf16 [NRED][256]
__global__ __launch_bounds__(256) void addmean_ln2_kernel(
    const float* __restrict__ x, const int* __restrict__ index,
    const int* __restrict__ r2f, const int* __restrict__ f2r,
    const unsigned short* __restrict__ sums, const float* __restrict__ cnts,
    const float* __restrict__ w, const float* __restrict__ b,
    float* __restrict__ x2, unsigned short* __restrict__ ln2b)
{
  int wave = threadIdx.x >> 6, lane = threadIdx.x & 63;
  int r = blockIdx.x * 4 + wave;
  if (r >= NRED_N) return;
  int j = f2r[r];
  int s = index[r2f[j]];
  float inv = 1.0f / fmaxf(cnts[s], 1.0f);
  uint2 sr = *(const uint2*)&sums[(size_t)s * C_DIM + (lane << 2)];
  float4 sv = make_float4(bf2f((unsigned short)(sr.x & 0xFFFF)),
                          bf2f((unsigned short)(sr.x >> 16)),
                          bf2f((unsigned short)(sr.y & 0xFFFF)),
                          bf2f((unsigned short)(sr.y >> 16)));
  float4 xv = *(const float4*)&x[(size_t)r * C_DIM + (lane << 2)];
  float4 o = make_float4(xv.x + sv.x * inv, xv.y + sv.y * inv,
                         xv.z + sv.z * inv, xv.w + sv.w * inv);
  *(float4*)&x2[(size_t)r * C_DIM + (lane << 2)] = o;
  // fused LN2
  float ssum = o.x + o.y + o.z + o.w;
  float sq = o.x*o.x + o.y*o.y + o.z*o.z + o.w*o.w;
  ssum = wave_reduce_sum(ssum);
  sq   = wave_reduce_sum(sq);
  float mean = ssum * (1.0f / 256.0f);
  float var  = sq * (1.0f / 256.0f) - mean * mean;
  float rstd = rsqrtf(var + 1e-5f);
  float4 wv = *(const float4*)&w[lane << 2];
  float4 bv = *(const float4*)&b[lane << 2];
  float ox = (o.x - mean) * rstd * wv.x + bv.x;
  float oy = (o.y - mean) * rstd * wv.y + bv.y;
  float oz = (o.z - mean) * rstd * wv.z + bv.z;
  float ow = (o.w - mean) * rstd * wv.w + bv.w;
  unsigned u0 = f2bf(ox) | ((unsigned)f2bf(oy) << 16);
  unsigned u1 = f2bf(oz) | ((unsigned)f2bf(ow) << 16);
  *(uint2*)&ln2b[(size_t)r * C_DIM + (lane << 2)] = make_uint2(u0, u1);
}

// --------------------------------------- FFN1 + gated SiLU fused (bf16 out)
// BM=64; 1D grid 1564, XCD-swizzled: bn = L&1 (fastest), bm = L>>1.
__global__ __launch_bounds__(256) void ffn1_act_kernel(
    const unsigned short* __restrict__ A, const unsigned short* __restrict__ B,
    unsigned short* __restrict__ act, int M)
{
  __shared__ unsigned short As[64 * 32];
  __shared__ unsigned short Bas[128 * 32];
  __shared__ unsigned short Bgs[128 * 32];
  const int tid = threadIdx.x;
  const int lane = tid & 63, w = tid >> 6;
  const int l15 = lane & 15, g = lane >> 4;
  const int L = xcd_logical(blockIdx.x, gridDim.x);
  const int bn = L & 1;
  const int bm = (L >> 1) * 64;
  floatx4 acc_a[4][2] = {}, acc_g[4][2] = {};
  const int sr = (lane >> 2);
  const int sk = (lane & 3) << 3;
  for (int k0 = 0; k0 < 256; k0 += 32) {
    {                                           // 4 A stripes, 1/wave
      const unsigned short* ga = A + (size_t)(bm + w * 16 + sr) * 256 + k0 + sk;
      __builtin_amdgcn_global_load_lds(
          (const __attribute__((address_space(1))) void*)ga,
          (__attribute__((address_space(3))) void*)&As[w * 512], 16, 0, 0);
    }
#pragma unroll
    for (int c = 0; c < 2; ++c) {               // 8 stripes each for Ba, Bg
      int stripe = w * 2 + c;
      const unsigned short* gba = B + (size_t)(bn * 128 + stripe * 16 + sr) * 256 + k0 + sk;
      const unsigned short* gbg = B + (size_t)(256 + bn * 128 + stripe * 16 + sr) * 256 + k0 + sk;
      __builtin_amdgcn_global_load_lds(
          (const __attribute__((address_space(1))) void*)gba,
          (__attribute__((address_space(3))) void*)&Bas[stripe * 512], 16, 0, 0);
      __builtin_amdgcn_global_load_lds(
          (const __attribute__((address_space(1))) void*)gbg,
          (__attribute__((address_space(3))) void*)&Bgs[stripe * 512], 16, 0, 0);
    }
    __syncthreads();
    const int kb = g << 3;
    short8 af[4], ba[2], bg2[2];
#pragma unroll
    for (int m = 0; m < 4; ++m)
      af[m] = *(const short8*)&As[(m * 16 + l15) * 32 + kb];
#pragma unroll
    for (int n = 0; n < 2; ++n) {
      ba[n]  = *(const short8*)&Bas[(w * 32 + n * 16 + l15) * 32 + kb];
      bg2[n] = *(const short8*)&Bgs[(w * 32 + n * 16 + l15) * 32 + kb];
    }
#pragma unroll
    for (int m = 0; m < 4; ++m)
#pragma unroll
      for (int n = 0; n < 2; ++n) {
        acc_a[m][n] = __builtin_amdgcn_mfma_f32_16x16x32_bf16(
            af[m], ba[n], acc_a[m][n], 0, 0, 0);
        acc_g[m][n] = __builtin_amdgcn_mfma_f32_16x16x32_bf16(
            af[m], bg2[n], acc_g[m][n], 0, 0, 0);
      }
    __syncthreads();
  }
  const int crow0 = bm + (g << 2);
  const int ccol0 = bn * 128 + w * 32 + l15;
  const float LOG2E = 1.4426950408889634f;
#pragma unroll
  for (int m = 0; m < 4; ++m) {
#pragma unroll
    for (int j = 0; j < 4; ++j) {
      int row = crow0 + m * 16 + j;
      if (row >= M) continue;
      size_t off = (size_t)row * 256 + ccol0;
#pragma unroll
      for (int n = 0; n < 2; ++n) {
        float a = acc_a[m][n][j];
        float gg = acc_g[m][n][j];
        float eneg = fast_exp2(-gg * LOG2E);
        float v = a * gg * fast_rcp(1.0f + eneg);
        act[off + n * 16] = f2bf(v);
      }
    }
  }
}

// ======================================================================
extern "C" void kernel_launch(void* const* d_in, const int* in_sizes, int n_in,
                              void* d_out, int out_size, void* d_ws, size_t ws_size,
                              hipStream_t stream)
{
  const float* x    = (const float*)d_in[0];
  const float* pos  = (const float*)d_in[1];
  const int*   index= (const int*)d_in[2];
  const int*   r2f  = (const int*)d_in[3];
  const int*   f2r  = (const int*)d_in[4];
  const float* n1w  = (const float*)d_in[5];
  const float* n1b  = (const float*)d_in[6];
  const float* qw   = (const float*)d_in[7];
  const float* kw   = (const float*)d_in[8];
  const float* vw   = (const float*)d_in[9];
  const float* ow   = (const float*)d_in[10];
  const float* n2w  = (const float*)d_in[11];
  const float* n2b  = (const float*)d_in[12];
  const float* w1   = (const float*)d_in[13];
  const float* w2   = (const float*)d_in[14];
  float* out = (float*)d_out;

  // ---- workspace layout (ws = 256 MiB)
  char* ws = (char*)d_ws;
  unsigned short* xnbf = (unsigned short*)(ws);               // [0, 33.5M)
  unsigned short* qhh  = (unsigned short*)(ws + 33554432);    // [33.5M, 67.1M)
  unsigned short* khh  = (unsigned short*)(ws + 67108864);    // [67.1M, 100.7M)
  unsigned short* vhh  = (unsigned short*)(ws + 100663296);   // [100.7M, 134.2M)
  float* x2   = (float*)(ws + 134217728);  // [134.2M, 185.4M)
  float* cnts = (float*)(ws + 185417728);  // 0.2MB
  unsigned short* wbf = (unsigned short*)(ws + 185617728);    // 0.98MB
  unsigned short* sums = (unsigned short*)(ws + 186646528);   // bf16, 25.6MB
  unsigned short* qwb = wbf;
  unsigned short* kwb = wbf + 65536;
  unsigned short* vwb = wbf + 2 * 65536;
  unsigned short* owb = wbf + 3 * 65536;
  unsigned short* w1b = wbf + 4 * 65536;   // 131072 elems
  unsigned short* w2b = wbf + 6 * 65536;
  // aliases (lifetimes):
  unsigned short* attn_out = xnbf;  // xnbf dead after QKV
  unsigned short* ln2b = xnbf;      // attn_out dead after O-proj
  unsigned short* actb = qhh;       // qhh dead after attention

  // 0. zero-init atomic targets and weight cvt
  hipMemsetAsync(sums, 0, (size_t)NRED_N * C_DIM * 2, stream);
  hipMemsetAsync(cnts, 0, (size_t)NRED_N * 4, stream);
  cvt_all_kernel<<<448, 256, 0, stream>>>(qw, kw, vw, ow, w1, w2,
                                          qwb, kwb, vwb, owb, w1b, w2b);
  // 1. gather + LN1 (+ fused segment count)
  ln_kernel<<<NFULL_N / 4, 256, 0, stream>>>(x, r2f, n1w, n1b, xnbf, NFULL_N,
                                             index, cnts);
  // 2. fused QKV projection + RoPE epilogue -> per-head bf16 (XCD-swizzled)
  const float C1 = 0.26339891f;   // (1/sqrt(30)) * log2(e), folded into q
  qkv_kernel<<<2048, 256, 0, stream>>>(xnbf, qwb, kwb, vwb, pos, r2f,
                                       qhh, khh, vhh, C1);
  // 3. MFMA attention -> attn_out bf16 [65536][256]
  attn_mfma_kernel<<<NE_N * HEADS, 512, 0, stream>>>(qhh, khh, vhh, attn_out);
  // 4+5. O projection fused with packed-bf16 segment scatter (mode 4)
  gemm_bf16<<<2048, 256, 0, stream>>>(attn_out, owb, sums, nullptr,
                                      index, r2f, NFULL_N, C_DIM, C_DIM, 4);
  // 6-7. x2 = x + gathered mean; LN2 fused (bf16 sums in)
  addmean_ln2_kernel<<<(NRED_N + 3) / 4, 256, 0, stream>>>(
      x, index, r2f, f2r, sums, cnts, n2w, n2b, x2, ln2b);
  // 8-9. FFN1 + gated SiLU fused (bf16 out)
  ffn1_act_kernel<<<1564, 256, 0, stream>>>(ln2b, w1b, actb, NRED_N);
  // 10. FFN2 + residual -> out
  gemm_bf16<<<1564, 256, 0, stream>>>(actb, w2b, out, x2,
                                      nullptr, nullptr, NRED_N, C_DIM, C_DIM, 0);
}

// Round 18
// 313.477 us; speedup vs baseline: 1.1643x; 1.0907x over previous
//
#include <hip/hip_runtime.h>
#include <hip/hip_bf16.h>
#include <cstddef>

#define C_DIM 256
#define HEADS 8
#define HD 32
#define NPTS 512
#define NFULL_N 65536
#define NRED_N 50000
#define NE_N 128

typedef __attribute__((ext_vector_type(8))) short short8;
typedef __attribute__((ext_vector_type(4))) float floatx4;
typedef __attribute__((ext_vector_type(4))) unsigned uintx4;

// ---------------------------------------------------------------- utilities
__device__ __forceinline__ float wave_reduce_sum(float v) {
#pragma unroll
  for (int off = 1; off < 64; off <<= 1) v += __shfl_xor(v, off, 64);
  return v;
}

__device__ __forceinline__ unsigned short f2bf(float f) {
  union { float f; unsigned u; } x; x.f = f;
  unsigned r = x.u + 0x7FFF + ((x.u >> 16) & 1);   // round-to-nearest-even
  return (unsigned short)(r >> 16);
}

__device__ __forceinline__ float bf2f(unsigned short u) {
  union { unsigned u; float f; } x; x.u = ((unsigned)u) << 16;
  return x.f;
}

__device__ __forceinline__ float fast_exp2(float x) {
#if __has_builtin(__builtin_amdgcn_exp2f)
  return __builtin_amdgcn_exp2f(x);
#else
  return exp2f(x);
#endif
}

__device__ __forceinline__ float fast_rcp(float x) {
#if __has_builtin(__builtin_amdgcn_rcpf)
  return __builtin_amdgcn_rcpf(x);
#else
  return 1.0f / x;
#endif
}

// XCD-aware bijective block remap: dispatch id -> logical id such that each
// XCD (hw: id % 8) owns a CONTIGUOUS logical range (per-XCD L2 reuse).
__device__ __forceinline__ int xcd_logical(int bid, int nwg) {
  int q = nwg >> 3, r = nwg & 7;
  int xcd = bid & 7, s = bid >> 3;
  int base = (xcd < r) ? xcd * (q + 1) : r * (q + 1) + (xcd - r) * q;
  return base + s;
}

// --------------------------------------------- all weights fp32 -> bf16, 1 launch
__global__ __launch_bounds__(256) void cvt_all_kernel(
    const float* __restrict__ qw, const float* __restrict__ kw,
    const float* __restrict__ vw, const float* __restrict__ ow,
    const float* __restrict__ w1, const float* __restrict__ w2,
    unsigned short* __restrict__ qwb, unsigned short* __restrict__ kwb,
    unsigned short* __restrict__ vwb, unsigned short* __restrict__ owb,
    unsigned short* __restrict__ w1b, unsigned short* __restrict__ w2b)
{
  int i = blockIdx.x * 256 + threadIdx.x;          // float4 index, total 114688
  const float* src; unsigned short* dst; int o;
  if      (i <  16384) { src = qw; dst = qwb; o = i; }
  else if (i <  32768) { src = kw; dst = kwb; o = i - 16384; }
  else if (i <  49152) { src = vw; dst = vwb; o = i - 32768; }
  else if (i <  65536) { src = ow; dst = owb; o = i - 49152; }
  else if (i <  98304) { src = w1; dst = w1b; o = i - 65536; }
  else                 { src = w2; dst = w2b; o = i - 98304; }
  float4 v = *(const float4*)&src[o << 2];
  unsigned u0 = f2bf(v.x) | ((unsigned)f2bf(v.y) << 16);
  unsigned u1 = f2bf(v.z) | ((unsigned)f2bf(v.w) << 16);
  *(uint2*)&dst[o << 2] = make_uint2(u0, u1);
}

// ------------------------- LayerNorm1 (gather, bf16 out) + fused segment cnt
__global__ __launch_bounds__(256) void ln_kernel(
    const float* __restrict__ x, const int* __restrict__ gidx,
    const float* __restrict__ w, const float* __restrict__ b,
    unsigned short* __restrict__ out, int nrows,
    const int* __restrict__ index, float* __restrict__ cnts)
{
  int wave = threadIdx.x >> 6, lane = threadIdx.x & 63;
  int row = blockIdx.x * 4 + wave;
  if (row >= nrows) return;
  int src = gidx ? gidx[row] : row;
  if (cnts && lane == 0) atomicAdd(&cnts[index[src]], 1.0f);
  const float* xr = x + (size_t)src * C_DIM;
  float4 v = *(const float4*)&xr[lane << 2];
  float s  = v.x + v.y + v.z + v.w;
  float sq = v.x*v.x + v.y*v.y + v.z*v.z + v.w*v.w;
  s  = wave_reduce_sum(s);
  sq = wave_reduce_sum(sq);
  float mean = s * (1.0f / 256.0f);
  float var  = sq * (1.0f / 256.0f) - mean * mean;
  float rstd = rsqrtf(var + 1e-5f);
  float4 wv = *(const float4*)&w[lane << 2];
  float4 bv = *(const float4*)&b[lane << 2];
  float ox = (v.x - mean) * rstd * wv.x + bv.x;
  float oy = (v.y - mean) * rstd * wv.y + bv.y;
  float oz = (v.z - mean) * rstd * wv.z + bv.z;
  float ow = (v.w - mean) * rstd * wv.w + bv.w;
  unsigned u0 = f2bf(ox) | ((unsigned)f2bf(oy) << 16);
  unsigned u1 = f2bf(oz) | ((unsigned)f2bf(ow) << 16);
  *(uint2*)&out[(size_t)row * C_DIM + (lane << 2)] = make_uint2(u0, u1);
}

// ---------------------------------------- fused QKV projection (bf16 per-head)
// 1D grid 2048, XCD-swizzled: logical L -> bn = L&3 (fastest), bm = L>>2.
// The 4 blocks sharing an A-tile run contiguously on ONE XCD -> L2 reuse.
__global__ __launch_bounds__(256) void qkv_kernel(
    const unsigned short* __restrict__ A,
    const unsigned short* __restrict__ Bq, const unsigned short* __restrict__ Bk,
    const unsigned short* __restrict__ Bv,
    unsigned short* __restrict__ qo, unsigned short* __restrict__ ko,
    unsigned short* __restrict__ vo)
{
  __shared__ unsigned short As[128 * 32];
  __shared__ unsigned short Bqs[64 * 32];
  __shared__ unsigned short Bks[64 * 32];
  __shared__ unsigned short Bvs[64 * 32];
  const int tid = threadIdx.x;
  const int lane = tid & 63, w = tid >> 6;
  const int wr = w >> 1, wc = w & 1;
  const int l15 = lane & 15, g = lane >> 4;
  const int L = xcd_logical(blockIdx.x, 2048);
  const int bn = L & 3;                     // 64-col slice (fastest)
  const int bm = (L >> 2) * 128;
  floatx4 acc[3][4][2] = {};
  const int sr = lane >> 2;
  const int sk = (lane & 3) << 3;
  for (int k0 = 0; k0 < 256; k0 += 32) {
#pragma unroll
    for (int c = 0; c < 2; ++c) {               // 8 A stripes, 2/wave
      int stripe = w * 2 + c;
      const unsigned short* ga = A + (size_t)(bm + stripe * 16 + sr) * 256 + k0 + sk;
      __builtin_amdgcn_global_load_lds(
          (const __attribute__((address_space(1))) void*)ga,
          (__attribute__((address_space(3))) void*)&As[stripe * 512], 16, 0, 0);
    }
#pragma unroll
    for (int c = 0; c < 3; ++c) {               // 12 B stripes, 3/wave
      int idx = w * 3 + c;                      // 0..11
      int t = idx >> 2, rs = idx & 3;
      const unsigned short* Bt = (t == 0) ? Bq : (t == 1) ? Bk : Bv;
      unsigned short* ldst = (t == 0) ? &Bqs[rs * 512]
                           : (t == 1) ? &Bks[rs * 512] : &Bvs[rs * 512];
      const unsigned short* gsrc = Bt + (size_t)(bn * 64 + rs * 16 + sr) * 256 + k0 + sk;
      __builtin_amdgcn_global_load_lds(
          (const __attribute__((address_space(1))) void*)gsrc,
          (__attribute__((address_space(3))) void*)ldst, 16, 0, 0);
    }
    __syncthreads();
    const int arow = wr * 64 + l15;
    const int brow = wc * 32 + l15;
    const int kb = g << 3;
    short8 af[4], bq[2], bk[2], bv[2];
#pragma unroll
    for (int m = 0; m < 4; ++m)
      af[m] = *(const short8*)&As[(arow + m * 16) * 32 + kb];
#pragma unroll
    for (int n = 0; n < 2; ++n) {
      bq[n] = *(const short8*)&Bqs[(brow + n * 16) * 32 + kb];
      bk[n] = *(const short8*)&Bks[(brow + n * 16) * 32 + kb];
      bv[n] = *(const short8*)&Bvs[(brow + n * 16) * 32 + kb];
    }
#pragma unroll
    for (int m = 0; m < 4; ++m)
#pragma unroll
      for (int n = 0; n < 2; ++n) {
        acc[0][m][n] = __builtin_amdgcn_mfma_f32_16x16x32_bf16(af[m], bq[n], acc[0][m][n], 0, 0, 0);
        acc[1][m][n] = __builtin_amdgcn_mfma_f32_16x16x32_bf16(af[m], bk[n], acc[1][m][n], 0, 0, 0);
        acc[2][m][n] = __builtin_amdgcn_mfma_f32_16x16x32_bf16(af[m], bv[n], acc[2][m][n], 0, 0, 0);
      }
    __syncthreads();
  }
  const int cgrp = bn * 2 + wc;                 // (col >> 5) of per-head layout
  const int crow0 = bm + wr * 64 + (g << 2);
#pragma unroll
  for (int m = 0; m < 4; ++m) {
#pragma unroll
    for (int j = 0; j < 4; ++j) {
      int row = crow0 + m * 16 + j;
      size_t hb = ((size_t)((row >> 9) * 8 + cgrp) * 512 + (row & 511)) * 32;
#pragma unroll
      for (int n = 0; n < 2; ++n) {
        int cc = n * 16 + l15;
        qo[hb + cc] = f2bf(acc[0][m][n][j]);
        ko[hb + cc] = f2bf(acc[1][m][n][j]);
        vo[hb + cc] = f2bf(acc[2][m][n][j]);
      }
    }
  }
}

// ------------------------------------------------------------- bf16 MFMA GEMM
// BM=64 x BN=128; 1D grid, XCD-swizzled: bn = L&1 (fastest), bm = L>>1.
// mode 0: fp32 row-major (+res). mode 3: bf16 row-major.
// mode 4: packed-bf16 atomic segment-scatter into bf16 sums.
__global__ __launch_bounds__(256) void gemm_bf16(
    const unsigned short* __restrict__ A, const unsigned short* __restrict__ B,
    void* __restrict__ Cv, const float* __restrict__ res,
    const int* __restrict__ seg_index, const int* __restrict__ seg_r2f,
    int M, int N, int K, int mode)
{
  __shared__ unsigned short As[64 * 32];
  __shared__ unsigned short Bs[128 * 32];
  const int tid = threadIdx.x;
  const int lane = tid & 63, w = tid >> 6;
  const int l15 = lane & 15, g = lane >> 4;
  const int L = xcd_logical(blockIdx.x, gridDim.x);
  const int bn = (L & 1) * 128;
  const int bm = (L >> 1) * 64;
  floatx4 acc[4][2] = {};
  const int sr = (lane >> 2);
  const int sk = (lane & 3) << 3;
  for (int k0 = 0; k0 < K; k0 += 32) {
    {                                           // 4 A stripes, 1/wave
      const unsigned short* ga = A + (size_t)(bm + w * 16 + sr) * K + k0 + sk;
      __builtin_amdgcn_global_load_lds(
          (const __attribute__((address_space(1))) void*)ga,
          (__attribute__((address_space(3))) void*)&As[w * 512], 16, 0, 0);
    }
#pragma unroll
    for (int c = 0; c < 2; ++c) {               // 8 B stripes, 2/wave
      int stripe = w * 2 + c;
      const unsigned short* gb = B + (size_t)(bn + stripe * 16 + sr) * K + k0 + sk;
      __builtin_amdgcn_global_load_lds(
          (const __attribute__((address_space(1))) void*)gb,
          (__attribute__((address_space(3))) void*)&Bs[stripe * 512], 16, 0, 0);
    }
    __syncthreads();
    const int kb = g << 3;
    short8 af[4], bfr[2];
#pragma unroll
    for (int m = 0; m < 4; ++m)
      af[m] = *(const short8*)&As[(m * 16 + l15) * 32 + kb];
#pragma unroll
    for (int n = 0; n < 2; ++n)
      bfr[n] = *(const short8*)&Bs[(w * 32 + n * 16 + l15) * 32 + kb];
#pragma unroll
    for (int m = 0; m < 4; ++m)
#pragma unroll
      for (int n = 0; n < 2; ++n)
        acc[m][n] = __builtin_amdgcn_mfma_f32_16x16x32_bf16(
            af[m], bfr[n], acc[m][n], 0, 0, 0);
    __syncthreads();
  }
  const int crow0 = bm + (g << 2);
  const int ccol0 = bn + w * 32 + l15;
#pragma unroll
  for (int m = 0; m < 4; ++m) {
#pragma unroll
    for (int j = 0; j < 4; ++j) {
      int row = crow0 + m * 16 + j;
      if (row >= M) continue;
      if (mode == 0) {
        float* C = (float*)Cv;
        size_t off = (size_t)row * N + ccol0;
#pragma unroll
        for (int n = 0; n < 2; ++n) {
          float v = acc[m][n][j];
          if (res) v += res[off + n * 16];
          C[off + n * 16] = v;
        }
      } else if (mode == 3) {
        unsigned short* C = (unsigned short*)Cv;
        size_t off = (size_t)row * N + ccol0;
#pragma unroll
        for (int n = 0; n < 2; ++n) C[off + n * 16] = f2bf(acc[m][n][j]);
      } else {  // mode 4: pk bf16 atomic scatter (wave spans 32 cols)
        unsigned short* S = (unsigned short*)Cv;
        int s = seg_index[seg_r2f[row]];
        int gbase = lane & 48;                 // g*16 (row-group origin)
        int le = (2 * l15) & 15;               // src l15 for even col
        int lo = (2 * l15 + 1) & 15;           // src l15 for odd col
        bool hi = (l15 >= 8);
        float va = acc[m][0][j];               // cols base + 0..15
        float vb = acc[m][1][j];               // cols base + 16..31
        float ae = __shfl(va, gbase + le, 64);
        float be = __shfl(vb, gbase + le, 64);
        float ao = __shfl(va, gbase + lo, 64);
        float bo = __shfl(vb, gbase + lo, 64);
        float ev = hi ? be : ae;               // col base + 2*l15
        float ov = hi ? bo : ao;               // col base + 2*l15 + 1
        unsigned pair = (unsigned)f2bf(ev) | ((unsigned)f2bf(ov) << 16);
        unsigned short* addr =
            S + (size_t)s * N + (bn + w * 32) + 2 * l15;
        asm volatile("global_atomic_pk_add_bf16 %0, %1, off"
                     :: "v"(addr), "v"(pair) : "memory");
      }
    }
  }
  if (mode == 4) asm volatile("s_waitcnt vmcnt(0)");  // drain asm atomics
}

// ------------------------------- RoPE in-place on bf16 per-head rows, q AND k
__global__ __launch_bounds__(256) void rope_qk_kernel(
    unsigned short* __restrict__ qb, unsigned short* __restrict__ kb,
    const float* __restrict__ pos, const int* __restrict__ r2f, float qscale)
{
  int row = blockIdx.x * 256 + threadIdx.x;
  if (row >= NFULL_N * HEADS) return;
  int e = row >> 12, p = row & 511;
  int j = (e << 9) | p;
  int pi = r2f[j];
  float pf[3];
  pf[0] = (pos[pi * 3 + 0] + 10.0f) * (1.0f / 35.0f);
  pf[1] = (pos[pi * 3 + 1] + 1.0f)  * (1.0f / 6.0f);
  pf[2] =  pos[pi * 3 + 2] * 0.5f;
  const float invts[5] = {1.0f, 0.3981071706f, 0.1584893192f,
                          0.0630957344f, 0.0251188643f};
  float sn[15], cs[15];
#pragma unroll
  for (int i = 0; i < 3; ++i)
#pragma unroll
    for (int t = 0; t < 5; ++t) {
      float theta = pf[i] * invts[t];
      __sincosf(theta, &sn[i * 5 + t], &cs[i * 5 + t]);
    }
  unsigned short* qr = qb + (size_t)row * 32;
  unsigned short* kr = kb + (size_t)row * 32;
  uint4 qraw[4], kraw[4];
#pragma unroll
  for (int u = 0; u < 4; ++u) { qraw[u] = *(const uint4*)&qr[u * 8];
                                kraw[u] = *(const uint4*)&kr[u * 8]; }
  float q[32], k[32];
  const unsigned short* qs = (const unsigned short*)qraw;
  const unsigned short* ks = (const unsigned short*)kraw;
#pragma unroll
  for (int d = 0; d < 32; ++d) { q[d] = bf2f(qs[d]); k[d] = bf2f(ks[d]); }
#pragma unroll
  for (int i = 0; i < 3; ++i)
#pragma unroll
    for (int t = 0; t < 5; ++t) {
      int fo = i * 10 + t, so = fo + 5, ti = i * 5 + t;
      float c0 = cs[ti], s0 = sn[ti];
      float qf = q[fo], qq = q[so];
      q[fo] = qf * c0 - qq * s0;
      q[so] = qq * c0 + qf * s0;
      float kf = k[fo], kk = k[so];
      k[fo] = kf * c0 - kk * s0;
      k[so] = kk * c0 + kf * s0;
    }
  q[30] = 0.f; q[31] = 0.f; k[30] = 0.f; k[31] = 0.f;
  unsigned qo[16], ko[16];
#pragma unroll
  for (int u = 0; u < 16; ++u) {
    qo[u] = f2bf(q[2*u] * qscale) | ((unsigned)f2bf(q[2*u+1] * qscale) << 16);
    ko[u] = f2bf(k[2*u]) | ((unsigned)f2bf(k[2*u+1]) << 16);
  }
#pragma unroll
  for (int u = 0; u < 4; ++u) {
    *(uint4*)&qr[u * 8] = make_uint4(qo[4*u], qo[4*u+1], qo[4*u+2], qo[4*u+3]);
    *(uint4*)&kr[u * 8] = make_uint4(ko[4*u], ko[4*u+1], ko[4*u+2], ko[4*u+3]);
  }
}

// ------------------------------------------------------------- MFMA attention
__global__ __launch_bounds__(512, 4) void attn_mfma_kernel(
    const unsigned short* __restrict__ qh, const unsigned short* __restrict__ kh,
    const unsigned short* __restrict__ vh, unsigned short* __restrict__ ob)
{
  __shared__ unsigned short K_lds[256 * 40];   // rows padded 32->40 bf16
  __shared__ unsigned short V_lds[32 * 264];   // [d][key] transposed, pad 264
  const int blk = blockIdx.x;
  const int e = blk >> 3, head = blk & 7;
  const int tid = threadIdx.x;
  const int w = tid >> 6, lane = tid & 63;
  const int l15 = lane & 15, g = lane >> 4;
  const size_t rowbase = (size_t)blk * 512;

  short8 qfrag[4];
#pragma unroll
  for (int qt = 0; qt < 4; ++qt) {
    size_t qrow = rowbase + w * 64 + qt * 16 + l15;
    qfrag[qt] = *(const short8*)&qh[qrow * 32 + g * 8];
  }
  floatx4 oacc[4][2] = {};
  floatx4 accl[4] = {};                   // lsum accumulators (ones-MFMA)
  const short one_bf = (short)0x3F80;     // bf16 1.0
  const short8 ones8 = {one_bf, one_bf, one_bf, one_bf,
                        one_bf, one_bf, one_bf, one_bf};
  const float C2 = 28.853900817779268f;  // 20 * log2(e)
  const floatx4 mc2 = {-C2, -C2, -C2, -C2};

  for (int stage = 0; stage < 2; ++stage) {
    const int kc0 = stage * 256;
    __syncthreads();
    // ---- K stage: plain loads, 2 threads/row, padded [256][40]
    {
      const unsigned short* khp = kh + (rowbase + kc0) * 32;
      int r = tid >> 1, half = tid & 1;
      uint4 a = *(const uint4*)&khp[(size_t)r * 32 + half * 16];
      uint4 b = *(const uint4*)&khp[(size_t)r * 32 + half * 16 + 8];
      *(uint4*)&K_lds[r * 40 + half * 16]     = a;
      *(uint4*)&K_lds[r * 40 + half * 16 + 8] = b;
    }
    // ---- V stage: bf16 rows -> transposed [d][key], column-permuted
    {
      int key = tid >> 1, dq = tid & 1;
      const unsigned short* vrow = vh + (rowbase + kc0 + key) * 32 + dq * 16;
      unsigned short tmp[16];
      *(uint4*)&tmp[0] = *(const uint4*)vrow;
      *(uint4*)&tmp[8] = *(const uint4*)(vrow + 8);
      int lam = key & 31;
      int pc = ((lam & 15) >> 2) * 8 + (lam & 3) + ((lam >> 4) << 2);
      int ccol = (key & ~31) + pc;
#pragma unroll
      for (int d = 0; d < 16; ++d)
        V_lds[(dq * 16 + d) * 264 + ccol] = tmp[d];
    }
    __syncthreads();
    // ---- compute: 8 chunks of 32 keys (setprio favors MFMA-phase waves)
    for (int c = 0; c < 8; ++c) {
      short8 kf0 = *(const short8*)&K_lds[(c * 32 + l15) * 40 + g * 8];
      short8 kf1 = *(const short8*)&K_lds[(c * 32 + 16 + l15) * 40 + g * 8];
      short8 vf0 = *(const short8*)&V_lds[l15 * 264 + c * 32 + g * 8];
      short8 vf1 = *(const short8*)&V_lds[(16 + l15) * 264 + c * 32 + g * 8];
      __builtin_amdgcn_s_setprio(1);
#pragma unroll
      for (int qt = 0; qt < 4; ++qt) {
        floatx4 s0 = __builtin_amdgcn_mfma_f32_16x16x32_bf16(kf0, qfrag[qt], mc2, 0, 0, 0);
        floatx4 s1 = __builtin_amdgcn_mfma_f32_16x16x32_bf16(kf1, qfrag[qt], mc2, 0, 0, 0);
        float p0 = fast_exp2(s0[0]), p1 = fast_exp2(s0[1]);
        float p2 = fast_exp2(s0[2]), p3 = fast_exp2(s0[3]);
        float p4 = fast_exp2(s1[0]), p5 = fast_exp2(s1[1]);
        float p6 = fast_exp2(s1[2]), p7 = fast_exp2(s1[3]);
        uintx4 uv = {
          __builtin_amdgcn_perm(__builtin_bit_cast(unsigned, p1),
                                __builtin_bit_cast(unsigned, p0), 0x07060302u),
          __builtin_amdgcn_perm(__builtin_bit_cast(unsigned, p3),
                                __builtin_bit_cast(unsigned, p2), 0x07060302u),
          __builtin_amdgcn_perm(__builtin_bit_cast(unsigned, p5),
                                __builtin_bit_cast(unsigned, p4), 0x07060302u),
          __builtin_amdgcn_perm(__builtin_bit_cast(unsigned, p7),
                                __builtin_bit_cast(unsigned, p6), 0x07060302u)};
        short8 ps8 = __builtin_bit_cast(short8, uv);
        oacc[qt][0] = __builtin_amdgcn_mfma_f32_16x16x32_bf16(ps8, vf0, oacc[qt][0], 0, 0, 0);
        oacc[qt][1] = __builtin_amdgcn_mfma_f32_16x16x32_bf16(ps8, vf1, oacc[qt][1], 0, 0, 0);
        accl[qt]    = __builtin_amdgcn_mfma_f32_16x16x32_bf16(ps8, ones8, accl[qt], 0, 0, 0);
      }
      __builtin_amdgcn_s_setprio(0);
    }
  }
  // ---- normalize + store: accl[qt][j] = full lsum for query row g*4+j
  const size_t obase = ((size_t)e * 512) * 256 + head * 32;
#pragma unroll
  for (int qt = 0; qt < 4; ++qt) {
#pragma unroll
    for (int j = 0; j < 4; ++j) {
      float inv = fast_rcp(accl[qt][j]);
      int p = w * 64 + qt * 16 + g * 4 + j;
      size_t off = obase + (size_t)p * 256 + l15;
      ob[off]      = f2bf(oacc[qt][0][j] * inv);
      ob[off + 16] = f2bf(oacc[qt][1][j] * inv);
    }
  }
}

// ---------------------------------- x2 = x + mean[seg-chain]; LN2 fused
// sums is bf16 [NRED][256]
__global__ __launch_bounds__(256) void addmean_ln2_kernel(
    const float* __restrict__ x, const int* __restrict__ index,
    const int* __restrict__ r2f, const int* __restrict__ f2r,
    const unsigned short* __restrict__ sums, const float* __restrict__ cnts,
    const float* __restrict__ w, const float* __restrict__ b,
    float* __restrict__ x2, unsigned short* __restrict__ ln2b)
{
  int wave = threadIdx.x >> 6, lane = threadIdx.x & 63;
  int r = blockIdx.x * 4 + wave;
  if (r >= NRED_N) return;
  int j = f2r[r];
  int s = index[r2f[j]];
  float inv = 1.0f / fmaxf(cnts[s], 1.0f);
  uint2 sr = *(const uint2*)&sums[(size_t)s * C_DIM + (lane << 2)];
  float4 sv = make_float4(bf2f((unsigned short)(sr.x & 0xFFFF)),
                          bf2f((unsigned short)(sr.x >> 16)),
                          bf2f((unsigned short)(sr.y & 0xFFFF)),
                          bf2f((unsigned short)(sr.y >> 16)));
  float4 xv = *(const float4*)&x[(size_t)r * C_DIM + (lane << 2)];
  float4 o = make_float4(xv.x + sv.x * inv, xv.y + sv.y * inv,
                         xv.z + sv.z * inv, xv.w + sv.w * inv);
  *(float4*)&x2[(size_t)r * C_DIM + (lane << 2)] = o;
  // fused LN2
  float ssum = o.x + o.y + o.z + o.w;
  float sq = o.x*o.x + o.y*o.y + o.z*o.z + o.w*o.w;
  ssum = wave_reduce_sum(ssum);
  sq   = wave_reduce_sum(sq);
  float mean = ssum * (1.0f / 256.0f);
  float var  = sq * (1.0f / 256.0f) - mean * mean;
  float rstd = rsqrtf(var + 1e-5f);
  float4 wv = *(const float4*)&w[lane << 2];
  float4 bv = *(const float4*)&b[lane << 2];
  float ox = (o.x - mean) * rstd * wv.x + bv.x;
  float oy = (o.y - mean) * rstd * wv.y + bv.y;
  float oz = (o.z - mean) * rstd * wv.z + bv.z;
  float ow = (o.w - mean) * rstd * wv.w + bv.w;
  unsigned u0 = f2bf(ox) | ((unsigned)f2bf(oy) << 16);
  unsigned u1 = f2bf(oz) | ((unsigned)f2bf(ow) << 16);
  *(uint2*)&ln2b[(size_t)r * C_DIM + (lane << 2)] = make_uint2(u0, u1);
}

// --------------------------------------- FFN1 + gated SiLU fused (bf16 out)
// BM=64; 1D grid 1564, XCD-swizzled: bn = L&1 (fastest), bm = L>>1.
__global__ __launch_bounds__(256) void ffn1_act_kernel(
    const unsigned short* __restrict__ A, const unsigned short* __restrict__ B,
    unsigned short* __restrict__ act, int M)
{
  __shared__ unsigned short As[64 * 32];
  __shared__ unsigned short Bas[128 * 32];
  __shared__ unsigned short Bgs[128 * 32];
  const int tid = threadIdx.x;
  const int lane = tid & 63, w = tid >> 6;
  const int l15 = lane & 15, g = lane >> 4;
  const int L = xcd_logical(blockIdx.x, gridDim.x);
  const int bn = L & 1;
  const int bm = (L >> 1) * 64;
  floatx4 acc_a[4][2] = {}, acc_g[4][2] = {};
  const int sr = (lane >> 2);
  const int sk = (lane & 3) << 3;
  for (int k0 = 0; k0 < 256; k0 += 32) {
    {                                           // 4 A stripes, 1/wave
      const unsigned short* ga = A + (size_t)(bm + w * 16 + sr) * 256 + k0 + sk;
      __builtin_amdgcn_global_load_lds(
          (const __attribute__((address_space(1))) void*)ga,
          (__attribute__((address_space(3))) void*)&As[w * 512], 16, 0, 0);
    }
#pragma unroll
    for (int c = 0; c < 2; ++c) {               // 8 stripes each for Ba, Bg
      int stripe = w * 2 + c;
      const unsigned short* gba = B + (size_t)(bn * 128 + stripe * 16 + sr) * 256 + k0 + sk;
      const unsigned short* gbg = B + (size_t)(256 + bn * 128 + stripe * 16 + sr) * 256 + k0 + sk;
      __builtin_amdgcn_global_load_lds(
          (const __attribute__((address_space(1))) void*)gba,
          (__attribute__((address_space(3))) void*)&Bas[stripe * 512], 16, 0, 0);
      __builtin_amdgcn_global_load_lds(
          (const __attribute__((address_space(1))) void*)gbg,
          (__attribute__((address_space(3))) void*)&Bgs[stripe * 512], 16, 0, 0);
    }
    __syncthreads();
    const int kb = g << 3;
    short8 af[4], ba[2], bg2[2];
#pragma unroll
    for (int m = 0; m < 4; ++m)
      af[m] = *(const short8*)&As[(m * 16 + l15) * 32 + kb];
#pragma unroll
    for (int n = 0; n < 2; ++n) {
      ba[n]  = *(const short8*)&Bas[(w * 32 + n * 16 + l15) * 32 + kb];
      bg2[n] = *(const short8*)&Bgs[(w * 32 + n * 16 + l15) * 32 + kb];
    }
#pragma unroll
    for (int m = 0; m < 4; ++m)
#pragma unroll
      for (int n = 0; n < 2; ++n) {
        acc_a[m][n] = __builtin_amdgcn_mfma_f32_16x16x32_bf16(
            af[m], ba[n], acc_a[m][n], 0, 0, 0);
        acc_g[m][n] = __builtin_amdgcn_mfma_f32_16x16x32_bf16(
            af[m], bg2[n], acc_g[m][n], 0, 0, 0);
      }
    __syncthreads();
  }
  const int crow0 = bm + (g << 2);
  const int ccol0 = bn * 128 + w * 32 + l15;
  const float LOG2E = 1.4426950408889634f;
#pragma unroll
  for (int m = 0; m < 4; ++m) {
#pragma unroll
    for (int j = 0; j < 4; ++j) {
      int row = crow0 + m * 16 + j;
      if (row >= M) continue;
      size_t off = (size_t)row * 256 + ccol0;
#pragma unroll
      for (int n = 0; n < 2; ++n) {
        float a = acc_a[m][n][j];
        float gg = acc_g[m][n][j];
        float eneg = fast_exp2(-gg * LOG2E);
        float v = a * gg * fast_rcp(1.0f + eneg);
        act[off + n * 16] = f2bf(v);
      }
    }
  }
}

// ======================================================================
extern "C" void kernel_launch(void* const* d_in, const int* in_sizes, int n_in,
                              void* d_out, int out_size, void* d_ws, size_t ws_size,
                              hipStream_t stream)
{
  const float* x    = (const float*)d_in[0];
  const float* pos  = (const float*)d_in[1];
  const int*   index= (const int*)d_in[2];
  const int*   r2f  = (const int*)d_in[3];
  const int*   f2r  = (const int*)d_in[4];
  const float* n1w  = (const float*)d_in[5];
  const float* n1b  = (const float*)d_in[6];
  const float* qw   = (const float*)d_in[7];
  const float* kw   = (const float*)d_in[8];
  const float* vw   = (const float*)d_in[9];
  const float* ow   = (const float*)d_in[10];
  const float* n2w  = (const float*)d_in[11];
  const float* n2b  = (const float*)d_in[12];
  const float* w1   = (const float*)d_in[13];
  const float* w2   = (const float*)d_in[14];
  float* out = (float*)d_out;

  // ---- workspace layout (ws = 256 MiB)
  char* ws = (char*)d_ws;
  unsigned short* xnbf = (unsigned short*)(ws);               // [0, 33.5M)
  unsigned short* qhh  = (unsigned short*)(ws + 33554432);    // [33.5M, 67.1M)
  unsigned short* khh  = (unsigned short*)(ws + 67108864);    // [67.1M, 100.7M)
  unsigned short* vhh  = (unsigned short*)(ws + 100663296);   // [100.7M, 134.2M)
  float* x2   = (float*)(ws + 134217728);  // [134.2M, 185.4M)
  float* cnts = (float*)(ws + 185417728);  // 0.2MB
  unsigned short* wbf = (unsigned short*)(ws + 185617728);    // 0.98MB
  unsigned short* sums = (unsigned short*)(ws + 186646528);   // bf16, 25.6MB
  unsigned short* qwb = wbf;
  unsigned short* kwb = wbf + 65536;
  unsigned short* vwb = wbf + 2 * 65536;
  unsigned short* owb = wbf + 3 * 65536;
  unsigned short* w1b = wbf + 4 * 65536;   // 131072 elems
  unsigned short* w2b = wbf + 6 * 65536;
  // aliases (lifetimes):
  unsigned short* attn_out = xnbf;  // xnbf dead after QKV
  unsigned short* ln2b = xnbf;      // attn_out dead after O-proj
  unsigned short* actb = qhh;       // qhh dead after attention

  // 0. zero-init atomic targets and weight cvt
  hipMemsetAsync(sums, 0, (size_t)NRED_N * C_DIM * 2, stream);
  hipMemsetAsync(cnts, 0, (size_t)NRED_N * 4, stream);
  cvt_all_kernel<<<448, 256, 0, stream>>>(qw, kw, vw, ow, w1, w2,
                                          qwb, kwb, vwb, owb, w1b, w2b);
  // 1. gather + LN1 (+ fused segment count)
  ln_kernel<<<NFULL_N / 4, 256, 0, stream>>>(x, r2f, n1w, n1b, xnbf, NFULL_N,
                                             index, cnts);
  // 2. fused QKV projection -> per-head bf16 (XCD-swizzled 1D grid)
  qkv_kernel<<<2048, 256, 0, stream>>>(xnbf, qwb, kwb, vwb, qhh, khh, vhh);
  // 3. fused RoPE on q,k (q pre-scaled by C1)
  const float C1 = 0.26339891f;   // (1/sqrt(30)) * log2(e)
  rope_qk_kernel<<<NFULL_N * HEADS / 256, 256, 0, stream>>>(qhh, khh, pos, r2f, C1);
  // 4. MFMA attention -> attn_out bf16 [65536][256]
  attn_mfma_kernel<<<NE_N * HEADS, 512, 0, stream>>>(qhh, khh, vhh, attn_out);
  // 5+6. O projection fused with packed-bf16 segment scatter (mode 4)
  gemm_bf16<<<2048, 256, 0, stream>>>(attn_out, owb, sums, nullptr,
                                      index, r2f, NFULL_N, C_DIM, C_DIM, 4);
  // 7-8. x2 = x + gathered mean; LN2 fused (bf16 sums in)
  addmean_ln2_kernel<<<(NRED_N + 3) / 4, 256, 0, stream>>>(
      x, index, r2f, f2r, sums, cnts, n2w, n2b, x2, ln2b);
  // 9-10. FFN1 + gated SiLU fused (bf16 out)
  ffn1_act_kernel<<<1564, 256, 0, stream>>>(ln2b, w1b, actb, NRED_N);
  // 11. FFN2 + residual -> out
  gemm_bf16<<<1564, 256, 0, stream>>>(actb, w2b, out, x2,
                                      nullptr, nullptr, NRED_N, C_DIM, C_DIM, 0);
}

// Round 19
// 295.441 us; speedup vs baseline: 1.2353x; 1.0610x over previous
//
#include <hip/hip_runtime.h>
#include <hip/hip_bf16.h>
#include <cstddef>

#define C_DIM 256
#define HEADS 8
#define HD 32
#define NPTS 512
#define NFULL_N 65536
#define NRED_N 50000
#define NE_N 128

typedef __attribute__((ext_vector_type(8))) short short8;
typedef __attribute__((ext_vector_type(4))) float floatx4;
typedef __attribute__((ext_vector_type(4))) unsigned uintx4;

// ---------------------------------------------------------------- utilities
__device__ __forceinline__ float wave_reduce_sum(float v) {
#pragma unroll
  for (int off = 1; off < 64; off <<= 1) v += __shfl_xor(v, off, 64);
  return v;
}

__device__ __forceinline__ unsigned short f2bf(float f) {
  union { float f; unsigned u; } x; x.f = f;
  unsigned r = x.u + 0x7FFF + ((x.u >> 16) & 1);   // round-to-nearest-even
  return (unsigned short)(r >> 16);
}

__device__ __forceinline__ float bf2f(unsigned short u) {
  union { unsigned u; float f; } x; x.u = ((unsigned)u) << 16;
  return x.f;
}

__device__ __forceinline__ float fast_exp2(float x) {
#if __has_builtin(__builtin_amdgcn_exp2f)
  return __builtin_amdgcn_exp2f(x);
#else
  return exp2f(x);
#endif
}

__device__ __forceinline__ float fast_rcp(float x) {
#if __has_builtin(__builtin_amdgcn_rcpf)
  return __builtin_amdgcn_rcpf(x);
#else
  return 1.0f / x;
#endif
}

// XCD-aware bijective block remap: dispatch id -> logical id such that each
// XCD (hw: id % 8) owns a CONTIGUOUS logical range (per-XCD L2 reuse).
__device__ __forceinline__ int xcd_logical(int bid, int nwg) {
  int q = nwg >> 3, r = nwg & 7;
  int xcd = bid & 7, s = bid >> 3;
  int base = (xcd < r) ? xcd * (q + 1) : r * (q + 1) + (xcd - r) * q;
  return base + s;
}

// --------------------------------------------- all weights fp32 -> bf16, 1 launch
__global__ __launch_bounds__(256) void cvt_all_kernel(
    const float* __restrict__ qw, const float* __restrict__ kw,
    const float* __restrict__ vw, const float* __restrict__ ow,
    const float* __restrict__ w1, const float* __restrict__ w2,
    unsigned short* __restrict__ qwb, unsigned short* __restrict__ kwb,
    unsigned short* __restrict__ vwb, unsigned short* __restrict__ owb,
    unsigned short* __restrict__ w1b, unsigned short* __restrict__ w2b)
{
  int i = blockIdx.x * 256 + threadIdx.x;          // float4 index, total 114688
  const float* src; unsigned short* dst; int o;
  if      (i <  16384) { src = qw; dst = qwb; o = i; }
  else if (i <  32768) { src = kw; dst = kwb; o = i - 16384; }
  else if (i <  49152) { src = vw; dst = vwb; o = i - 32768; }
  else if (i <  65536) { src = ow; dst = owb; o = i - 49152; }
  else if (i <  98304) { src = w1; dst = w1b; o = i - 65536; }
  else                 { src = w2; dst = w2b; o = i - 98304; }
  float4 v = *(const float4*)&src[o << 2];
  unsigned u0 = f2bf(v.x) | ((unsigned)f2bf(v.y) << 16);
  unsigned u1 = f2bf(v.z) | ((unsigned)f2bf(v.w) << 16);
  *(uint2*)&dst[o << 2] = make_uint2(u0, u1);
}

// ------------------------- LayerNorm1 (gather, bf16 out) + fused segment cnt
__global__ __launch_bounds__(256) void ln_kernel(
    const float* __restrict__ x, const int* __restrict__ gidx,
    const float* __restrict__ w, const float* __restrict__ b,
    unsigned short* __restrict__ out, int nrows,
    const int* __restrict__ index, float* __restrict__ cnts)
{
  int wave = threadIdx.x >> 6, lane = threadIdx.x & 63;
  int row = blockIdx.x * 4 + wave;
  if (row >= nrows) return;
  int src = gidx ? gidx[row] : row;
  if (cnts && lane == 0) atomicAdd(&cnts[index[src]], 1.0f);
  const float* xr = x + (size_t)src * C_DIM;
  float4 v = *(const float4*)&xr[lane << 2];
  float s  = v.x + v.y + v.z + v.w;
  float sq = v.x*v.x + v.y*v.y + v.z*v.z + v.w*v.w;
  s  = wave_reduce_sum(s);
  sq = wave_reduce_sum(sq);
  float mean = s * (1.0f / 256.0f);
  float var  = sq * (1.0f / 256.0f) - mean * mean;
  float rstd = rsqrtf(var + 1e-5f);
  float4 wv = *(const float4*)&w[lane << 2];
  float4 bv = *(const float4*)&b[lane << 2];
  float ox = (v.x - mean) * rstd * wv.x + bv.x;
  float oy = (v.y - mean) * rstd * wv.y + bv.y;
  float oz = (v.z - mean) * rstd * wv.z + bv.z;
  float ow = (v.w - mean) * rstd * wv.w + bv.w;
  unsigned u0 = f2bf(ox) | ((unsigned)f2bf(oy) << 16);
  unsigned u1 = f2bf(oz) | ((unsigned)f2bf(ow) << 16);
  *(uint2*)&out[(size_t)row * C_DIM + (lane << 2)] = make_uint2(u0, u1);
}

// ---------------------------------------- fused QKV projection (bf16 per-head)
// 1D grid 2048, XCD-swizzled: logical L -> bn = L&3 (fastest), bm = L>>2.
__global__ __launch_bounds__(256) void qkv_kernel(
    const unsigned short* __restrict__ A,
    const unsigned short* __restrict__ Bq, const unsigned short* __restrict__ Bk,
    const unsigned short* __restrict__ Bv,
    unsigned short* __restrict__ qo, unsigned short* __restrict__ ko,
    unsigned short* __restrict__ vo)
{
  __shared__ unsigned short As[128 * 32];
  __shared__ unsigned short Bqs[64 * 32];
  __shared__ unsigned short Bks[64 * 32];
  __shared__ unsigned short Bvs[64 * 32];
  const int tid = threadIdx.x;
  const int lane = tid & 63, w = tid >> 6;
  const int wr = w >> 1, wc = w & 1;
  const int l15 = lane & 15, g = lane >> 4;
  const int L = xcd_logical(blockIdx.x, 2048);
  const int bn = L & 3;                     // 64-col slice (fastest)
  const int bm = (L >> 2) * 128;
  floatx4 acc[3][4][2] = {};
  const int sr = lane >> 2;
  const int sk = (lane & 3) << 3;
  for (int k0 = 0; k0 < 256; k0 += 32) {
#pragma unroll
    for (int c = 0; c < 2; ++c) {               // 8 A stripes, 2/wave
      int stripe = w * 2 + c;
      const unsigned short* ga = A + (size_t)(bm + stripe * 16 + sr) * 256 + k0 + sk;
      __builtin_amdgcn_global_load_lds(
          (const __attribute__((address_space(1))) void*)ga,
          (__attribute__((address_space(3))) void*)&As[stripe * 512], 16, 0, 0);
    }
#pragma unroll
    for (int c = 0; c < 3; ++c) {               // 12 B stripes, 3/wave
      int idx = w * 3 + c;                      // 0..11
      int t = idx >> 2, rs = idx & 3;
      const unsigned short* Bt = (t == 0) ? Bq : (t == 1) ? Bk : Bv;
      unsigned short* ldst = (t == 0) ? &Bqs[rs * 512]
                           : (t == 1) ? &Bks[rs * 512] : &Bvs[rs * 512];
      const unsigned short* gsrc = Bt + (size_t)(bn * 64 + rs * 16 + sr) * 256 + k0 + sk;
      __builtin_amdgcn_global_load_lds(
          (const __attribute__((address_space(1))) void*)gsrc,
          (__attribute__((address_space(3))) void*)ldst, 16, 0, 0);
    }
    __syncthreads();
    const int arow = wr * 64 + l15;
    const int brow = wc * 32 + l15;
    const int kb = g << 3;
    short8 af[4], bq[2], bk[2], bv[2];
#pragma unroll
    for (int m = 0; m < 4; ++m)
      af[m] = *(const short8*)&As[(arow + m * 16) * 32 + kb];
#pragma unroll
    for (int n = 0; n < 2; ++n) {
      bq[n] = *(const short8*)&Bqs[(brow + n * 16) * 32 + kb];
      bk[n] = *(const short8*)&Bks[(brow + n * 16) * 32 + kb];
      bv[n] = *(const short8*)&Bvs[(brow + n * 16) * 32 + kb];
    }
#pragma unroll
    for (int m = 0; m < 4; ++m)
#pragma unroll
      for (int n = 0; n < 2; ++n) {
        acc[0][m][n] = __builtin_amdgcn_mfma_f32_16x16x32_bf16(af[m], bq[n], acc[0][m][n], 0, 0, 0);
        acc[1][m][n] = __builtin_amdgcn_mfma_f32_16x16x32_bf16(af[m], bk[n], acc[1][m][n], 0, 0, 0);
        acc[2][m][n] = __builtin_amdgcn_mfma_f32_16x16x32_bf16(af[m], bv[n], acc[2][m][n], 0, 0, 0);
      }
    __syncthreads();
  }
  const int cgrp = bn * 2 + wc;                 // (col >> 5) of per-head layout
  const int crow0 = bm + wr * 64 + (g << 2);
#pragma unroll
  for (int m = 0; m < 4; ++m) {
#pragma unroll
    for (int j = 0; j < 4; ++j) {
      int row = crow0 + m * 16 + j;
      size_t hb = ((size_t)((row >> 9) * 8 + cgrp) * 512 + (row & 511)) * 32;
#pragma unroll
      for (int n = 0; n < 2; ++n) {
        int cc = n * 16 + l15;
        qo[hb + cc] = f2bf(acc[0][m][n][j]);
        ko[hb + cc] = f2bf(acc[1][m][n][j]);
        vo[hb + cc] = f2bf(acc[2][m][n][j]);
      }
    }
  }
}

// ------------------------------------------------------------- bf16 MFMA GEMM
// BM=64 x BN=128; 1D grid, XCD-swizzled: bn = L&1 (fastest), bm = L>>1.
// mode 0: fp32 row-major out (+ optional bf16 residual). mode 3: bf16 row-major.
// mode 4: packed-bf16 atomic segment-scatter into bf16 sums.
__global__ __launch_bounds__(256) void gemm_bf16(
    const unsigned short* __restrict__ A, const unsigned short* __restrict__ B,
    void* __restrict__ Cv, const unsigned short* __restrict__ res,
    const int* __restrict__ seg_index, const int* __restrict__ seg_r2f,
    int M, int N, int K, int mode)
{
  __shared__ unsigned short As[64 * 32];
  __shared__ unsigned short Bs[128 * 32];
  const int tid = threadIdx.x;
  const int lane = tid & 63, w = tid >> 6;
  const int l15 = lane & 15, g = lane >> 4;
  const int L = xcd_logical(blockIdx.x, gridDim.x);
  const int bn = (L & 1) * 128;
  const int bm = (L >> 1) * 64;
  floatx4 acc[4][2] = {};
  const int sr = (lane >> 2);
  const int sk = (lane & 3) << 3;
  for (int k0 = 0; k0 < K; k0 += 32) {
    {                                           // 4 A stripes, 1/wave
      const unsigned short* ga = A + (size_t)(bm + w * 16 + sr) * K + k0 + sk;
      __builtin_amdgcn_global_load_lds(
          (const __attribute__((address_space(1))) void*)ga,
          (__attribute__((address_space(3))) void*)&As[w * 512], 16, 0, 0);
    }
#pragma unroll
    for (int c = 0; c < 2; ++c) {               // 8 B stripes, 2/wave
      int stripe = w * 2 + c;
      const unsigned short* gb = B + (size_t)(bn + stripe * 16 + sr) * K + k0 + sk;
      __builtin_amdgcn_global_load_lds(
          (const __attribute__((address_space(1))) void*)gb,
          (__attribute__((address_space(3))) void*)&Bs[stripe * 512], 16, 0, 0);
    }
    __syncthreads();
    const int kb = g << 3;
    short8 af[4], bfr[2];
#pragma unroll
    for (int m = 0; m < 4; ++m)
      af[m] = *(const short8*)&As[(m * 16 + l15) * 32 + kb];
#pragma unroll
    for (int n = 0; n < 2; ++n)
      bfr[n] = *(const short8*)&Bs[(w * 32 + n * 16 + l15) * 32 + kb];
#pragma unroll
    for (int m = 0; m < 4; ++m)
#pragma unroll
      for (int n = 0; n < 2; ++n)
        acc[m][n] = __builtin_amdgcn_mfma_f32_16x16x32_bf16(
            af[m], bfr[n], acc[m][n], 0, 0, 0);
    __syncthreads();
  }
  const int crow0 = bm + (g << 2);
  const int ccol0 = bn + w * 32 + l15;
#pragma unroll
  for (int m = 0; m < 4; ++m) {
#pragma unroll
    for (int j = 0; j < 4; ++j) {
      int row = crow0 + m * 16 + j;
      if (row >= M) continue;
      if (mode == 0) {
        float* C = (float*)Cv;
        size_t off = (size_t)row * N + ccol0;
#pragma unroll
        for (int n = 0; n < 2; ++n) {
          float v = acc[m][n][j];
          if (res) v += bf2f(res[off + n * 16]);
          C[off + n * 16] = v;
        }
      } else if (mode == 3) {
        unsigned short* C = (unsigned short*)Cv;
        size_t off = (size_t)row * N + ccol0;
#pragma unroll
        for (int n = 0; n < 2; ++n) C[off + n * 16] = f2bf(acc[m][n][j]);
      } else {  // mode 4: pk bf16 atomic scatter (wave spans 32 cols)
        unsigned short* S = (unsigned short*)Cv;
        int s = seg_index[seg_r2f[row]];
        int gbase = lane & 48;                 // g*16 (row-group origin)
        int le = (2 * l15) & 15;               // src l15 for even col
        int lo = (2 * l15 + 1) & 15;           // src l15 for odd col
        bool hi = (l15 >= 8);
        float va = acc[m][0][j];               // cols base + 0..15
        float vb = acc[m][1][j];               // cols base + 16..31
        float ae = __shfl(va, gbase + le, 64);
        float be = __shfl(vb, gbase + le, 64);
        float ao = __shfl(va, gbase + lo, 64);
        float bo = __shfl(vb, gbase + lo, 64);
        float ev = hi ? be : ae;               // col base + 2*l15
        float ov = hi ? bo : ao;               // col base + 2*l15 + 1
        unsigned pair = (unsigned)f2bf(ev) | ((unsigned)f2bf(ov) << 16);
        unsigned short* addr =
            S + (size_t)s * N + (bn + w * 32) + 2 * l15;
        asm volatile("global_atomic_pk_add_bf16 %0, %1, off"
                     :: "v"(addr), "v"(pair) : "memory");
      }
    }
  }
  if (mode == 4) asm volatile("s_waitcnt vmcnt(0)");  // drain asm atomics
}

// ------------------------------- RoPE in-place on bf16 per-head rows, q AND k
__global__ __launch_bounds__(256) void rope_qk_kernel(
    unsigned short* __restrict__ qb, unsigned short* __restrict__ kb,
    const float* __restrict__ pos, const int* __restrict__ r2f, float qscale)
{
  int row = blockIdx.x * 256 + threadIdx.x;
  if (row >= NFULL_N * HEADS) return;
  int e = row >> 12, p = row & 511;
  int j = (e << 9) | p;
  int pi = r2f[j];
  float pf[3];
  pf[0] = (pos[pi * 3 + 0] + 10.0f) * (1.0f / 35.0f);
  pf[1] = (pos[pi * 3 + 1] + 1.0f)  * (1.0f / 6.0f);
  pf[2] =  pos[pi * 3 + 2] * 0.5f;
  const float invts[5] = {1.0f, 0.3981071706f, 0.1584893192f,
                          0.0630957344f, 0.0251188643f};
  float sn[15], cs[15];
#pragma unroll
  for (int i = 0; i < 3; ++i)
#pragma unroll
    for (int t = 0; t < 5; ++t) {
      float theta = pf[i] * invts[t];
      __sincosf(theta, &sn[i * 5 + t], &cs[i * 5 + t]);
    }
  unsigned short* qr = qb + (size_t)row * 32;
  unsigned short* kr = kb + (size_t)row * 32;
  uint4 qraw[4], kraw[4];
#pragma unroll
  for (int u = 0; u < 4; ++u) { qraw[u] = *(const uint4*)&qr[u * 8];
                                kraw[u] = *(const uint4*)&kr[u * 8]; }
  float q[32], k[32];
  const unsigned short* qs = (const unsigned short*)qraw;
  const unsigned short* ks = (const unsigned short*)kraw;
#pragma unroll
  for (int d = 0; d < 32; ++d) { q[d] = bf2f(qs[d]); k[d] = bf2f(ks[d]); }
#pragma unroll
  for (int i = 0; i < 3; ++i)
#pragma unroll
    for (int t = 0; t < 5; ++t) {
      int fo = i * 10 + t, so = fo + 5, ti = i * 5 + t;
      float c0 = cs[ti], s0 = sn[ti];
      float qf = q[fo], qq = q[so];
      q[fo] = qf * c0 - qq * s0;
      q[so] = qq * c0 + qf * s0;
      float kf = k[fo], kk = k[so];
      k[fo] = kf * c0 - kk * s0;
      k[so] = kk * c0 + kf * s0;
    }
  q[30] = 0.f; q[31] = 0.f; k[30] = 0.f; k[31] = 0.f;
  unsigned qo[16], ko[16];
#pragma unroll
  for (int u = 0; u < 16; ++u) {
    qo[u] = f2bf(q[2*u] * qscale) | ((unsigned)f2bf(q[2*u+1] * qscale) << 16);
    ko[u] = f2bf(k[2*u]) | ((unsigned)f2bf(k[2*u+1]) << 16);
  }
#pragma unroll
  for (int u = 0; u < 4; ++u) {
    *(uint4*)&qr[u * 8] = make_uint4(qo[4*u], qo[4*u+1], qo[4*u+2], qo[4*u+3]);
    *(uint4*)&kr[u * 8] = make_uint4(ko[4*u], ko[4*u+1], ko[4*u+2], ko[4*u+3]);
  }
}

// ------------------------------------------------------------- MFMA attention
__global__ __launch_bounds__(512, 4) void attn_mfma_kernel(
    const unsigned short* __restrict__ qh, const unsigned short* __restrict__ kh,
    const unsigned short* __restrict__ vh, unsigned short* __restrict__ ob)
{
  __shared__ unsigned short K_lds[256 * 40];   // rows padded 32->40 bf16
  __shared__ unsigned short V_lds[32 * 264];   // [d][key] transposed, pad 264
  const int blk = blockIdx.x;
  const int e = blk >> 3, head = blk & 7;
  const int tid = threadIdx.x;
  const int w = tid >> 6, lane = tid & 63;
  const int l15 = lane & 15, g = lane >> 4;
  const size_t rowbase = (size_t)blk * 512;

  short8 qfrag[4];
#pragma unroll
  for (int qt = 0; qt < 4; ++qt) {
    size_t qrow = rowbase + w * 64 + qt * 16 + l15;
    qfrag[qt] = *(const short8*)&qh[qrow * 32 + g * 8];
  }
  floatx4 oacc[4][2] = {};
  floatx4 accl[4] = {};                   // lsum accumulators (ones-MFMA)
  const short one_bf = (short)0x3F80;     // bf16 1.0
  const short8 ones8 = {one_bf, one_bf, one_bf, one_bf,
                        one_bf, one_bf, one_bf, one_bf};
  const float C2 = 28.853900817779268f;  // 20 * log2(e)
  const floatx4 mc2 = {-C2, -C2, -C2, -C2};

  for (int stage = 0; stage < 2; ++stage) {
    const int kc0 = stage * 256;
    __syncthreads();
    // ---- K stage: plain loads, 2 threads/row, padded [256][40]
    {
      const unsigned short* khp = kh + (rowbase + kc0) * 32;
      int r = tid >> 1, half = tid & 1;
      uint4 a = *(const uint4*)&khp[(size_t)r * 32 + half * 16];
      uint4 b = *(const uint4*)&khp[(size_t)r * 32 + half * 16 + 8];
      *(uint4*)&K_lds[r * 40 + half * 16]     = a;
      *(uint4*)&K_lds[r * 40 + half * 16 + 8] = b;
    }
    // ---- V stage: bf16 rows -> transposed [d][key], column-permuted
    {
      int key = tid >> 1, dq = tid & 1;
      const unsigned short* vrow = vh + (rowbase + kc0 + key) * 32 + dq * 16;
      unsigned short tmp[16];
      *(uint4*)&tmp[0] = *(const uint4*)vrow;
      *(uint4*)&tmp[8] = *(const uint4*)(vrow + 8);
      int lam = key & 31;
      int pc = ((lam & 15) >> 2) * 8 + (lam & 3) + ((lam >> 4) << 2);
      int ccol = (key & ~31) + pc;
#pragma unroll
      for (int d = 0; d < 16; ++d)
        V_lds[(dq * 16 + d) * 264 + ccol] = tmp[d];
    }
    __syncthreads();
    // ---- compute: 8 chunks of 32 keys (setprio favors MFMA-phase waves)
    for (int c = 0; c < 8; ++c) {
      short8 kf0 = *(const short8*)&K_lds[(c * 32 + l15) * 40 + g * 8];
      short8 kf1 = *(const short8*)&K_lds[(c * 32 + 16 + l15) * 40 + g * 8];
      short8 vf0 = *(const short8*)&V_lds[l15 * 264 + c * 32 + g * 8];
      short8 vf1 = *(const short8*)&V_lds[(16 + l15) * 264 + c * 32 + g * 8];
      __builtin_amdgcn_s_setprio(1);
#pragma unroll
      for (int qt = 0; qt < 4; ++qt) {
        floatx4 s0 = __builtin_amdgcn_mfma_f32_16x16x32_bf16(kf0, qfrag[qt], mc2, 0, 0, 0);
        floatx4 s1 = __builtin_amdgcn_mfma_f32_16x16x32_bf16(kf1, qfrag[qt], mc2, 0, 0, 0);
        float p0 = fast_exp2(s0[0]), p1 = fast_exp2(s0[1]);
        float p2 = fast_exp2(s0[2]), p3 = fast_exp2(s0[3]);
        float p4 = fast_exp2(s1[0]), p5 = fast_exp2(s1[1]);
        float p6 = fast_exp2(s1[2]), p7 = fast_exp2(s1[3]);
        uintx4 uv = {
          __builtin_amdgcn_perm(__builtin_bit_cast(unsigned, p1),
                                __builtin_bit_cast(unsigned, p0), 0x07060302u),
          __builtin_amdgcn_perm(__builtin_bit_cast(unsigned, p3),
                                __builtin_bit_cast(unsigned, p2), 0x07060302u),
          __builtin_amdgcn_perm(__builtin_bit_cast(unsigned, p5),
                                __builtin_bit_cast(unsigned, p4), 0x07060302u),
          __builtin_amdgcn_perm(__builtin_bit_cast(unsigned, p7),
                                __builtin_bit_cast(unsigned, p6), 0x07060302u)};
        short8 ps8 = __builtin_bit_cast(short8, uv);
        oacc[qt][0] = __builtin_amdgcn_mfma_f32_16x16x32_bf16(ps8, vf0, oacc[qt][0], 0, 0, 0);
        oacc[qt][1] = __builtin_amdgcn_mfma_f32_16x16x32_bf16(ps8, vf1, oacc[qt][1], 0, 0, 0);
        accl[qt]    = __builtin_amdgcn_mfma_f32_16x16x32_bf16(ps8, ones8, accl[qt], 0, 0, 0);
      }
      __builtin_amdgcn_s_setprio(0);
    }
  }
  // ---- normalize + store: accl[qt][j] = full lsum for query row g*4+j
  const size_t obase = ((size_t)e * 512) * 256 + head * 32;
#pragma unroll
  for (int qt = 0; qt < 4; ++qt) {
#pragma unroll
    for (int j = 0; j < 4; ++j) {
      float inv = fast_rcp(accl[qt][j]);
      int p = w * 64 + qt * 16 + g * 4 + j;
      size_t off = obase + (size_t)p * 256 + l15;
      ob[off]      = f2bf(oacc[qt][0][j] * inv);
      ob[off + 16] = f2bf(oacc[qt][1][j] * inv);
    }
  }
}

// ---------------------------------- x2 = x + mean[seg-chain]; LN2 fused
// sums is bf16 [NRED][256]; x2 written as bf16 (residual carried to FFN2)
__global__ __launch_bounds__(256) void addmean_ln2_kernel(
    const float* __restrict__ x, const int* __restrict__ index,
    const int* __restrict__ r2f, const int* __restrict__ f2r,
    const unsigned short* __restrict__ sums, const float* __restrict__ cnts,
    const float* __restrict__ w, const float* __restrict__ b,
    unsigned short* __restrict__ x2, unsigned short* __restrict__ ln2b)
{
  int wave = threadIdx.x >> 6, lane = threadIdx.x & 63;
  int r = blockIdx.x * 4 + wave;
  if (r >= NRED_N) return;
  int j = f2r[r];
  int s = index[r2f[j]];
  float inv = 1.0f / fmaxf(cnts[s], 1.0f);
  uint2 sr = *(const uint2*)&sums[(size_t)s * C_DIM + (lane << 2)];
  float4 sv = make_float4(bf2f((unsigned short)(sr.x & 0xFFFF)),
                          bf2f((unsigned short)(sr.x >> 16)),
                          bf2f((unsigned short)(sr.y & 0xFFFF)),
                          bf2f((unsigned short)(sr.y >> 16)));
  float4 xv = *(const float4*)&x[(size_t)r * C_DIM + (lane << 2)];
  float4 o = make_float4(xv.x + sv.x * inv, xv.y + sv.y * inv,
                         xv.z + sv.z * inv, xv.w + sv.w * inv);
  unsigned p0 = f2bf(o.x) | ((unsigned)f2bf(o.y) << 16);
  unsigned p1 = f2bf(o.z) | ((unsigned)f2bf(o.w) << 16);
  *(uint2*)&x2[(size_t)r * C_DIM + (lane << 2)] = make_uint2(p0, p1);
  // fused LN2 (full fp32 path)
  float ssum = o.x + o.y + o.z + o.w;
  float sq = o.x*o.x + o.y*o.y + o.z*o.z + o.w*o.w;
  ssum = wave_reduce_sum(ssum);
  sq   = wave_reduce_sum(sq);
  float mean = ssum * (1.0f / 256.0f);
  float var  = sq * (1.0f / 256.0f) - mean * mean;
  float rstd = rsqrtf(var + 1e-5f);
  float4 wv = *(const float4*)&w[lane << 2];
  float4 bv = *(const float4*)&b[lane << 2];
  float ox = (o.x - mean) * rstd * wv.x + bv.x;
  float oy = (o.y - mean) * rstd * wv.y + bv.y;
  float oz = (o.z - mean) * rstd * wv.z + bv.z;
  float ow = (o.w - mean) * rstd * wv.w + bv.w;
  unsigned u0 = f2bf(ox) | ((unsigned)f2bf(oy) << 16);
  unsigned u1 = f2bf(oz) | ((unsigned)f2bf(ow) << 16);
  *(uint2*)&ln2b[(size_t)r * C_DIM + (lane << 2)] = make_uint2(u0, u1);
}

// --------------------------------------- FFN1 + gated SiLU fused (bf16 out)
// BM=64; 1D grid 1564, XCD-swizzled: bn = L&1 (fastest), bm = L>>1.
__global__ __launch_bounds__(256) void ffn1_act_kernel(
    const unsigned short* __restrict__ A, const unsigned short* __restrict__ B,
    unsigned short* __restrict__ act, int M)
{
  __shared__ unsigned short As[64 * 32];
  __shared__ unsigned short Bas[128 * 32];
  __shared__ unsigned short Bgs[128 * 32];
  const int tid = threadIdx.x;
  const int lane = tid & 63, w = tid >> 6;
  const int l15 = lane & 15, g = lane >> 4;
  const int L = xcd_logical(blockIdx.x, gridDim.x);
  const int bn = L & 1;
  const int bm = (L >> 1) * 64;
  floatx4 acc_a[4][2] = {}, acc_g[4][2] = {};
  const int sr = (lane >> 2);
  const int sk = (lane & 3) << 3;
  for (int k0 = 0; k0 < 256; k0 += 32) {
    {                                           // 4 A stripes, 1/wave
      const unsigned short* ga = A + (size_t)(bm + w * 16 + sr) * 256 + k0 + sk;
      __builtin_amdgcn_global_load_lds(
          (const __attribute__((address_space(1))) void*)ga,
          (__attribute__((address_space(3))) void*)&As[w * 512], 16, 0, 0);
    }
#pragma unroll
    for (int c = 0; c < 2; ++c) {               // 8 stripes each for Ba, Bg
      int stripe = w * 2 + c;
      const unsigned short* gba = B + (size_t)(bn * 128 + stripe * 16 + sr) * 256 + k0 + sk;
      const unsigned short* gbg = B + (size_t)(256 + bn * 128 + stripe * 16 + sr) * 256 + k0 + sk;
      __builtin_amdgcn_global_load_lds(
          (const __attribute__((address_space(1))) void*)gba,
          (__attribute__((address_space(3))) void*)&Bas[stripe * 512], 16, 0, 0);
      __builtin_amdgcn_global_load_lds(
          (const __attribute__((address_space(1))) void*)gbg,
          (__attribute__((address_space(3))) void*)&Bgs[stripe * 512], 16, 0, 0);
    }
    __syncthreads();
    const int kb = g << 3;
    short8 af[4], ba[2], bg2[2];
#pragma unroll
    for (int m = 0; m < 4; ++m)
      af[m] = *(const short8*)&As[(m * 16 + l15) * 32 + kb];
#pragma unroll
    for (int n = 0; n < 2; ++n) {
      ba[n]  = *(const short8*)&Bas[(w * 32 + n * 16 + l15) * 32 + kb];
      bg2[n] = *(const short8*)&Bgs[(w * 32 + n * 16 + l15) * 32 + kb];
    }
#pragma unroll
    for (int m = 0; m < 4; ++m)
#pragma unroll
      for (int n = 0; n < 2; ++n) {
        acc_a[m][n] = __builtin_amdgcn_mfma_f32_16x16x32_bf16(
            af[m], ba[n], acc_a[m][n], 0, 0, 0);
        acc_g[m][n] = __builtin_amdgcn_mfma_f32_16x16x32_bf16(
            af[m], bg2[n], acc_g[m][n], 0, 0, 0);
      }
    __syncthreads();
  }
  const int crow0 = bm + (g << 2);
  const int ccol0 = bn * 128 + w * 32 + l15;
  const float LOG2E = 1.4426950408889634f;
#pragma unroll
  for (int m = 0; m < 4; ++m) {
#pragma unroll
    for (int j = 0; j < 4; ++j) {
      int row = crow0 + m * 16 + j;
      if (row >= M) continue;
      size_t off = (size_t)row * 256 + ccol0;
#pragma unroll
      for (int n = 0; n < 2; ++n) {
        float a = acc_a[m][n][j];
        float gg = acc_g[m][n][j];
        float eneg = fast_exp2(-gg * LOG2E);
        float v = a * gg * fast_rcp(1.0f + eneg);
        act[off + n * 16] = f2bf(v);
      }
    }
  }
}

// ======================================================================
extern "C" void kernel_launch(void* const* d_in, const int* in_sizes, int n_in,
                              void* d_out, int out_size, void* d_ws, size_t ws_size,
                              hipStream_t stream)
{
  const float* x    = (const float*)d_in[0];
  const float* pos  = (const float*)d_in[1];
  const int*   index= (const int*)d_in[2];
  const int*   r2f  = (const int*)d_in[3];
  const int*   f2r  = (const int*)d_in[4];
  const float* n1w  = (const float*)d_in[5];
  const float* n1b  = (const float*)d_in[6];
  const float* qw   = (const float*)d_in[7];
  const float* kw   = (const float*)d_in[8];
  const float* vw   = (const float*)d_in[9];
  const float* ow   = (const float*)d_in[10];
  const float* n2w  = (const float*)d_in[11];
  const float* n2b  = (const float*)d_in[12];
  const float* w1   = (const float*)d_in[13];
  const float* w2   = (const float*)d_in[14];
  float* out = (float*)d_out;

  // ---- workspace layout (ws = 256 MiB)
  char* ws = (char*)d_ws;
  unsigned short* xnbf = (unsigned short*)(ws);               // [0, 33.5M)
  unsigned short* qhh  = (unsigned short*)(ws + 33554432);    // [33.5M, 67.1M)
  unsigned short* khh  = (unsigned short*)(ws + 67108864);    // [67.1M, 100.7M)
  unsigned short* vhh  = (unsigned short*)(ws + 100663296);   // [100.7M, 134.2M)
  unsigned short* x2   = (unsigned short*)(ws + 134217728);   // bf16, 25.6MB
  float* cnts = (float*)(ws + 185417728);  // 0.2MB
  unsigned short* wbf = (unsigned short*)(ws + 185617728);    // 0.98MB
  unsigned short* sums = (unsigned short*)(ws + 186646528);   // bf16, 25.6MB
  unsigned short* qwb = wbf;
  unsigned short* kwb = wbf + 65536;
  unsigned short* vwb = wbf + 2 * 65536;
  unsigned short* owb = wbf + 3 * 65536;
  unsigned short* w1b = wbf + 4 * 65536;   // 131072 elems
  unsigned short* w2b = wbf + 6 * 65536;
  // aliases (lifetimes):
  unsigned short* attn_out = xnbf;  // xnbf dead after QKV
  unsigned short* ln2b = xnbf;      // attn_out dead after O-proj
  unsigned short* actb = qhh;       // qhh dead after attention

  // 0. zero-init atomic targets and weight cvt
  hipMemsetAsync(sums, 0, (size_t)NRED_N * C_DIM * 2, stream);
  hipMemsetAsync(cnts, 0, (size_t)NRED_N * 4, stream);
  cvt_all_kernel<<<448, 256, 0, stream>>>(qw, kw, vw, ow, w1, w2,
                                          qwb, kwb, vwb, owb, w1b, w2b);
  // 1. gather + LN1 (+ fused segment count)
  ln_kernel<<<NFULL_N / 4, 256, 0, stream>>>(x, r2f, n1w, n1b, xnbf, NFULL_N,
                                             index, cnts);
  // 2. fused QKV projection -> per-head bf16 (XCD-swizzled 1D grid)
  qkv_kernel<<<2048, 256, 0, stream>>>(xnbf, qwb, kwb, vwb, qhh, khh, vhh);
  // 3. fused RoPE on q,k (q pre-scaled by C1)
  const float C1 = 0.26339891f;   // (1/sqrt(30)) * log2(e)
  rope_qk_kernel<<<NFULL_N * HEADS / 256, 256, 0, stream>>>(qhh, khh, pos, r2f, C1);
  // 4. MFMA attention -> attn_out bf16 [65536][256]
  attn_mfma_kernel<<<NE_N * HEADS, 512, 0, stream>>>(qhh, khh, vhh, attn_out);
  // 5+6. O projection fused with packed-bf16 segment scatter (mode 4)
  gemm_bf16<<<2048, 256, 0, stream>>>(attn_out, owb, sums, nullptr,
                                      index, r2f, NFULL_N, C_DIM, C_DIM, 4);
  // 7-8. x2 = x + gathered mean (bf16); LN2 fused
  addmean_ln2_kernel<<<(NRED_N + 3) / 4, 256, 0, stream>>>(
      x, index, r2f, f2r, sums, cnts, n2w, n2b, x2, ln2b);
  // 9-10. FFN1 + gated SiLU fused (bf16 out)
  ffn1_act_kernel<<<1564, 256, 0, stream>>>(ln2b, w1b, actb, NRED_N);
  // 11. FFN2 + bf16 residual -> fp32 out
  gemm_bf16<<<1564, 256, 0, stream>>>(actb, w2b, out, x2,
                                      nullptr, nullptr, NRED_N, C_DIM, C_DIM, 0);
}